// Round 3
// baseline (783.662 us; speedup 1.0000x reference)
//
#include <hip/hip_runtime.h>
#include <hip/hip_bf16.h>
#include <math.h>

typedef __attribute__((ext_vector_type(8))) short short8;
typedef __attribute__((ext_vector_type(4))) float f32x4;

__device__ __forceinline__ float bf2f(unsigned short u) {
    union { unsigned int i; float f; } c; c.i = ((unsigned int)u) << 16; return c.f;
}
__device__ __forceinline__ unsigned short f2bf(float f) {
    union { float f; unsigned int i; } c; c.f = f;
    unsigned int i = c.i;
    unsigned int r = (i + 0x7FFFu + ((i >> 16) & 1u)) >> 16;
    return (unsigned short)r;
}
// dtype-polymorphic load/store helpers
__device__ __forceinline__ float ldf(const float* p, size_t i) { return p[i]; }
__device__ __forceinline__ float ldf(const unsigned short* p, size_t i) { return bf2f(p[i]); }
__device__ __forceinline__ void stf(float* p, size_t i, float v) { p[i] = v; }
__device__ __forceinline__ void stf(unsigned short* p, size_t i, float v) { p[i] = f2bf(v); }

// ---------------- LayerNorm (fp32 input) -> bf16 output ----------------
__global__ __launch_bounds__(256) void ln_f32_kernel(
    const float* __restrict__ x, const float* __restrict__ g,
    const float* __restrict__ b, unsigned short* __restrict__ out) {
    const int row = blockIdx.x;
    const int t = threadIdx.x;
    const float* xr = x + (size_t)row * 1024;
    float4 raw = ((const float4*)xr)[t];
    float v0 = raw.x, v1 = raw.y, v2 = raw.z, v3 = raw.w;
    float s = v0 + v1 + v2 + v3;
    float ss = v0 * v0 + v1 * v1 + v2 * v2 + v3 * v3;
    for (int off = 32; off > 0; off >>= 1) {
        s += __shfl_down(s, off);
        ss += __shfl_down(ss, off);
    }
    __shared__ float red[8];
    __shared__ float stat[2];
    const int wave = t >> 6, lane = t & 63;
    if (lane == 0) { red[wave] = s; red[4 + wave] = ss; }
    __syncthreads();
    if (t == 0) {
        float st = red[0] + red[1] + red[2] + red[3];
        float sst = red[4] + red[5] + red[6] + red[7];
        float mu = st * (1.0f / 1024.0f);
        float var = sst * (1.0f / 1024.0f) - mu * mu;
        stat[0] = mu; stat[1] = rsqrtf(var + 1e-5f);
    }
    __syncthreads();
    const float mu = stat[0], rstd = stat[1];
    float4 gr = ((const float4*)g)[t];
    float4 br = ((const float4*)b)[t];
    ushort4 o;
    o.x = f2bf((v0 - mu) * rstd * gr.x + br.x);
    o.y = f2bf((v1 - mu) * rstd * gr.y + br.y);
    o.z = f2bf((v2 - mu) * rstd * gr.z + br.z);
    o.w = f2bf((v3 - mu) * rstd * gr.w + br.w);
    ((ushort4*)(out + (size_t)row * 1024))[t] = o;
}

// ---------------- LayerNorm (bf16 input) -> bf16 output ----------------
__global__ __launch_bounds__(256) void ln_bf16_kernel(
    const unsigned short* __restrict__ x, const float* __restrict__ g,
    const float* __restrict__ b, unsigned short* __restrict__ out) {
    const int row = blockIdx.x;
    const int t = threadIdx.x;
    const unsigned short* xr = x + (size_t)row * 1024;
    ushort4 raw = ((const ushort4*)xr)[t];
    float v0 = bf2f(raw.x), v1 = bf2f(raw.y), v2 = bf2f(raw.z), v3 = bf2f(raw.w);
    float s = v0 + v1 + v2 + v3;
    float ss = v0 * v0 + v1 * v1 + v2 * v2 + v3 * v3;
    for (int off = 32; off > 0; off >>= 1) {
        s += __shfl_down(s, off);
        ss += __shfl_down(ss, off);
    }
    __shared__ float red[8];
    __shared__ float stat[2];
    const int wave = t >> 6, lane = t & 63;
    if (lane == 0) { red[wave] = s; red[4 + wave] = ss; }
    __syncthreads();
    if (t == 0) {
        float st = red[0] + red[1] + red[2] + red[3];
        float sst = red[4] + red[5] + red[6] + red[7];
        float mu = st * (1.0f / 1024.0f);
        float var = sst * (1.0f / 1024.0f) - mu * mu;
        stat[0] = mu; stat[1] = rsqrtf(var + 1e-5f);
    }
    __syncthreads();
    const float mu = stat[0], rstd = stat[1];
    float4 gr = ((const float4*)g)[t];
    float4 br = ((const float4*)b)[t];
    ushort4 o;
    o.x = f2bf((v0 - mu) * rstd * gr.x + br.x);
    o.y = f2bf((v1 - mu) * rstd * gr.y + br.y);
    o.z = f2bf((v2 - mu) * rstd * gr.z + br.z);
    o.w = f2bf((v3 - mu) * rstd * gr.w + br.w);
    ((ushort4*)(out + (size_t)row * 1024))[t] = o;
}

// ---------------- Transpose+cast: fp32 in[R][C] -> bf16 out[C][R] ----------------
__global__ __launch_bounds__(256) void transpose_cast_kernel(
    const float* __restrict__ in, unsigned short* __restrict__ out, int R, int C) {
    __shared__ unsigned short tile[32][33];
    const int bx = blockIdx.x * 32, by = blockIdx.y * 32;
    const int tx = threadIdx.x & 31, ty = threadIdx.x >> 5;
    for (int i = 0; i < 32; i += 8)
        tile[ty + i][tx] = f2bf(in[(size_t)(by + ty + i) * C + bx + tx]);
    __syncthreads();
    for (int i = 0; i < 32; i += 8)
        out[(size_t)(bx + ty + i) * R + by + tx] = tile[tx][ty + i];
}

// ---------------- GEMM: C[M,N] = A[M,K] * Bt[N,K]^T + bias, fused epilogues ----
// 128x128 tile, BK=32, 4 waves (2x2), 16x16x32 bf16 MFMA, 4x4 acc/wave.
enum { EPI_QKV = 0, EPI_RES = 1, EPI_GELU = 2 };

template <int EPI, typename RT, typename OT>
__global__ __launch_bounds__(256) void gemm_bt(
    const unsigned short* __restrict__ A, const unsigned short* __restrict__ Bt,
    const float* __restrict__ bias, const RT* __restrict__ res,
    OT* __restrict__ o0, unsigned short* __restrict__ o1,
    unsigned short* __restrict__ o2, int M, int N, int K) {
    __shared__ __align__(16) unsigned short As[128 * 32];
    __shared__ __align__(16) unsigned short Bs[128 * 32];
    const int t = threadIdx.x;
    const int wave = t >> 6, lane = t & 63;
    const int lr = lane & 15, lq = lane >> 4;
    const int wm = (wave >> 1) * 64, wn = (wave & 1) * 64;
    const int m0 = blockIdx.y * 128, n0 = blockIdx.x * 128;
    f32x4 acc[4][4] = {};
    const int arow = t >> 2, acol = (t & 3) << 3;
    const unsigned short* ag = A + (size_t)(m0 + arow) * K + acol;
    const unsigned short* bg = Bt + (size_t)(n0 + arow) * K + acol;
    const size_t rstride = (size_t)64 * K;
    for (int k0 = 0; k0 < K; k0 += 32) {
        short8 a0 = *(const short8*)(ag + k0);
        short8 a1 = *(const short8*)(ag + rstride + k0);
        short8 b0 = *(const short8*)(bg + k0);
        short8 b1 = *(const short8*)(bg + rstride + k0);
        __syncthreads();  // previous iteration's fragment reads complete
        *(short8*)(As + t * 8) = a0;
        *(short8*)(As + 2048 + t * 8) = a1;
        *(short8*)(Bs + t * 8) = b0;
        *(short8*)(Bs + 2048 + t * 8) = b1;
        __syncthreads();
        short8 af[4], bfr[4];
#pragma unroll
        for (int i = 0; i < 4; i++) af[i] = *(const short8*)(As + (wm + i * 16 + lr) * 32 + lq * 8);
#pragma unroll
        for (int i = 0; i < 4; i++) bfr[i] = *(const short8*)(Bs + (wn + i * 16 + lr) * 32 + lq * 8);
#pragma unroll
        for (int mi = 0; mi < 4; mi++)
#pragma unroll
            for (int ni = 0; ni < 4; ni++)
                acc[mi][ni] = __builtin_amdgcn_mfma_f32_16x16x32_bf16(af[mi], bfr[ni], acc[mi][ni], 0, 0, 0);
    }
#pragma unroll
    for (int ni = 0; ni < 4; ni++) {
        const int col = n0 + wn + ni * 16 + lr;
        const float bv = bias[col];
#pragma unroll
        for (int mi = 0; mi < 4; mi++) {
#pragma unroll
            for (int r = 0; r < 4; r++) {
                const int row = m0 + wm + mi * 16 + lq * 4 + r;
                float val = acc[mi][ni][r] + bv;
                if (EPI == EPI_QKV) {
                    const int which = col >> 10, rem = col & 1023;
                    const int hn = rem >> 6, d = rem & 63;
                    const int bb = row >> 11, s = row & 2047;
                    const size_t bh = (size_t)(bb * 16 + hn);
                    if (which == 0) stf((unsigned short*)o0, (bh * 2048 + s) * 64 + d, val);
                    else if (which == 1) o1[(bh * 2048 + s) * 64 + d] = f2bf(val);
                    else o2[(bh * 64 + d) * 2048 + s] = f2bf(val);
                } else if (EPI == EPI_RES) {
                    val += ldf(res, (size_t)row * N + col);
                    stf(o0, (size_t)row * N + col, val);
                } else {  // EPI_GELU: exact gelu
                    val = 0.5f * val * (1.0f + erff(val * 0.70710678118654752f));
                    stf(o0, (size_t)row * N + col, val);
                }
            }
        }
    }
}

// ---------------- Flash attention, causal. Hd=64, S=2048, BH=64 ----------------
// q,k: [BH, S, 64]; vt: [BH, 64, S]; out: [B, S, 1024] bf16
__global__ __launch_bounds__(256) void attn_kernel(
    const unsigned short* __restrict__ qb, const unsigned short* __restrict__ kb,
    const unsigned short* __restrict__ vtb, unsigned short* __restrict__ aout) {
    const int qt = blockIdx.x, bh = blockIdx.y;
    const int bidx = bh >> 4, h = bh & 15;
    const int t = threadIdx.x, wave = t >> 6, lane = t & 63;
    const int lr = lane & 15, lq = lane >> 4;
    __shared__ __align__(16) unsigned short Ks[64 * 64];
    __shared__ __align__(16) unsigned short Vs[64 * 64];
    __shared__ __align__(16) unsigned short Ps[4][16 * 64];
    const unsigned short* qbase = qb + ((size_t)bh * 2048 + qt * 64) * 64;
    const unsigned short* kbase = kb + (size_t)bh * 2048 * 64;
    const unsigned short* vbase = vtb + (size_t)bh * 64 * 2048;
    short8 qf0 = *(const short8*)(qbase + (wave * 16 + lr) * 64 + lq * 8);
    short8 qf1 = *(const short8*)(qbase + (wave * 16 + lr) * 64 + 32 + lq * 8);
    f32x4 acc_o[4] = {};
    float m_i[4], l_i[4], alpha[4];
#pragma unroll
    for (int r = 0; r < 4; r++) { m_i[r] = -1e30f; l_i[r] = 0.0f; }
    const unsigned short* vg = vbase + (size_t)(t >> 3) * 2048 + ((t & 7) << 3);
    const int qrow0 = qt * 64 + wave * 16 + lq * 4;
    for (int kt = 0; kt <= qt; kt++) {
        const unsigned short* kg = kbase + kt * 4096;
        short8 kr0 = *(const short8*)(kg + t * 8);
        short8 kr1 = *(const short8*)(kg + 2048 + t * 8);
        short8 vr0 = *(const short8*)(vg + kt * 64);
        short8 vr1 = *(const short8*)(vg + 32 * 2048 + kt * 64);
        __syncthreads();
        *(short8*)(Ks + t * 8) = kr0;
        *(short8*)(Ks + 2048 + t * 8) = kr1;
        *(short8*)(Vs + t * 8) = vr0;
        *(short8*)(Vs + 2048 + t * 8) = vr1;
        __syncthreads();
        f32x4 s_acc[4];
#pragma unroll
        for (int ni = 0; ni < 4; ni++) {
            short8 kf0 = *(const short8*)(Ks + (ni * 16 + lr) * 64 + lq * 8);
            short8 kf1 = *(const short8*)(Ks + (ni * 16 + lr) * 64 + 32 + lq * 8);
            f32x4 z = {};
            z = __builtin_amdgcn_mfma_f32_16x16x32_bf16(qf0, kf0, z, 0, 0, 0);
            s_acc[ni] = __builtin_amdgcn_mfma_f32_16x16x32_bf16(qf1, kf1, z, 0, 0, 0);
        }
        float mcur[4];
#pragma unroll
        for (int r = 0; r < 4; r++) mcur[r] = -1e30f;
#pragma unroll
        for (int ni = 0; ni < 4; ni++) {
            const int kcol = kt * 64 + ni * 16 + lr;
#pragma unroll
            for (int r = 0; r < 4; r++) {
                float sv = s_acc[ni][r] * 0.125f;
                if (kcol > qrow0 + r) sv = -1e30f;
                s_acc[ni][r] = sv;
                mcur[r] = fmaxf(mcur[r], sv);
            }
        }
#pragma unroll
        for (int r = 0; r < 4; r++) {
#pragma unroll
            for (int off = 1; off < 16; off <<= 1) mcur[r] = fmaxf(mcur[r], __shfl_xor(mcur[r], off));
            const float mn = fmaxf(m_i[r], mcur[r]);
            alpha[r] = __expf(m_i[r] - mn);
            m_i[r] = mn;
        }
        float rsum[4] = {0.0f, 0.0f, 0.0f, 0.0f};
#pragma unroll
        for (int ni = 0; ni < 4; ni++)
#pragma unroll
            for (int r = 0; r < 4; r++) {
                const float p = __expf(s_acc[ni][r] - m_i[r]);
                s_acc[ni][r] = p;
                rsum[r] += p;
            }
#pragma unroll
        for (int r = 0; r < 4; r++) {
#pragma unroll
            for (int off = 1; off < 16; off <<= 1) rsum[r] += __shfl_xor(rsum[r], off);
            l_i[r] = l_i[r] * alpha[r] + rsum[r];
        }
#pragma unroll
        for (int ni = 0; ni < 4; ni++)
#pragma unroll
            for (int r = 0; r < 4; r++) {
                acc_o[ni][r] *= alpha[r];
                Ps[wave][(lq * 4 + r) * 64 + ni * 16 + lr] = f2bf(s_acc[ni][r]);
            }
        __syncthreads();
        short8 pf0 = *(const short8*)(&Ps[wave][lr * 64 + lq * 8]);
        short8 pf1 = *(const short8*)(&Ps[wave][lr * 64 + 32 + lq * 8]);
#pragma unroll
        for (int ni = 0; ni < 4; ni++) {
            short8 vf0 = *(const short8*)(Vs + (ni * 16 + lr) * 64 + lq * 8);
            short8 vf1 = *(const short8*)(Vs + (ni * 16 + lr) * 64 + 32 + lq * 8);
            acc_o[ni] = __builtin_amdgcn_mfma_f32_16x16x32_bf16(pf0, vf0, acc_o[ni], 0, 0, 0);
            acc_o[ni] = __builtin_amdgcn_mfma_f32_16x16x32_bf16(pf1, vf1, acc_o[ni], 0, 0, 0);
        }
    }
#pragma unroll
    for (int ni = 0; ni < 4; ni++)
#pragma unroll
        for (int r = 0; r < 4; r++) {
            const int q = qt * 64 + wave * 16 + lq * 4 + r;
            const size_t token = (size_t)bidx * 2048 + q;
            aout[token * 1024 + h * 64 + ni * 16 + lr] = f2bf(acc_o[ni][r] / l_i[r]);
        }
}

// ---------------- launch ----------------
extern "C" void kernel_launch(void* const* d_in, const int* in_sizes, int n_in,
                              void* d_out, int out_size, void* d_ws, size_t ws_size,
                              hipStream_t stream) {
    const float* x      = (const float*)d_in[0];
    const float* qkv_w  = (const float*)d_in[1];
    const float* qkv_b  = (const float*)d_in[2];
    const float* out_w  = (const float*)d_in[3];
    const float* out_b  = (const float*)d_in[4];
    const float* ffn1_w = (const float*)d_in[5];
    const float* ffn1_b = (const float*)d_in[6];
    const float* ffn2_w = (const float*)d_in[7];
    const float* ffn2_b = (const float*)d_in[8];
    const float* ln1_g  = (const float*)d_in[9];
    const float* ln1_b  = (const float*)d_in[10];
    const float* ln2_g  = (const float*)d_in[11];
    const float* ln2_b  = (const float*)d_in[12];
    float* out = (float*)d_out;
    char* W = (char*)d_ws;

    // byte offsets in workspace (all internal tensors bf16)
    unsigned short* normed = (unsigned short*)(W);                    // 16.78 MB
    unsigned short* x1     = (unsigned short*)(W + 16777216);         // 16.78 MB
    unsigned short* qbuf   = (unsigned short*)(W + 33554432);         // 16.78 MB
    unsigned short* kbuf   = (unsigned short*)(W + 50331648);         // 16.78 MB
    unsigned short* vbuf   = (unsigned short*)(W + 67108864);         // 16.78 MB
    unsigned short* attnb  = (unsigned short*)(W + 83886080);         // 16.78 MB
    unsigned short* hff    = (unsigned short*)(W + 33554432);         // 67.1 MB, reuses q/k/v/attn (dead)
    unsigned short* qkv_wt = (unsigned short*)(W + 100663296);        // 6.29 MB
    unsigned short* out_wt = (unsigned short*)(W + 106954752);        // 2.10 MB
    unsigned short* f1_wt  = (unsigned short*)(W + 109051904);        // 8.39 MB
    unsigned short* f2_wt  = (unsigned short*)(W + 117440512);        // 8.39 MB -> 125.8 MB total

    // Weight transpose+cast -> bf16 B^T (k-contiguous) layouts
    transpose_cast_kernel<<<dim3(3072 / 32, 1024 / 32), 256, 0, stream>>>(qkv_w, qkv_wt, 1024, 3072);
    transpose_cast_kernel<<<dim3(1024 / 32, 1024 / 32), 256, 0, stream>>>(out_w, out_wt, 1024, 1024);
    transpose_cast_kernel<<<dim3(4096 / 32, 1024 / 32), 256, 0, stream>>>(ffn1_w, f1_wt, 1024, 4096);
    transpose_cast_kernel<<<dim3(1024 / 32, 4096 / 32), 256, 0, stream>>>(ffn2_w, f2_wt, 4096, 1024);

    // LN1 (fp32 x -> bf16 normed)
    ln_f32_kernel<<<dim3(8192), 256, 0, stream>>>(x, ln1_g, ln1_b, normed);
    // QKV projection, scatter to q/k/v^T (bf16)
    gemm_bt<EPI_QKV, float, unsigned short><<<dim3(3072 / 128, 8192 / 128), 256, 0, stream>>>(
        normed, qkv_wt, qkv_b, nullptr, qbuf, kbuf, vbuf, 8192, 3072, 1024);
    // Causal flash attention
    attn_kernel<<<dim3(32, 64), 256, 0, stream>>>(qbuf, kbuf, vbuf, attnb);
    // Output projection + residual(x fp32) -> x1 (bf16)
    gemm_bt<EPI_RES, float, unsigned short><<<dim3(1024 / 128, 8192 / 128), 256, 0, stream>>>(
        attnb, out_wt, out_b, x, x1, nullptr, nullptr, 8192, 1024, 1024);
    // LN2 (bf16 x1 -> bf16 normed)
    ln_bf16_kernel<<<dim3(8192), 256, 0, stream>>>(x1, ln2_g, ln2_b, normed);
    // FFN1 + exact GELU -> hff (bf16)
    gemm_bt<EPI_GELU, float, unsigned short><<<dim3(4096 / 128, 8192 / 128), 256, 0, stream>>>(
        normed, f1_wt, ffn1_b, nullptr, hff, nullptr, nullptr, 8192, 4096, 1024);
    // FFN2 + residual(x1 bf16) -> out (fp32, d_out)
    gemm_bt<EPI_RES, unsigned short, float><<<dim3(1024 / 128, 8192 / 128), 256, 0, stream>>>(
        hff, f2_wt, ffn2_b, x1, out, nullptr, nullptr, 8192, 1024, 4096);
}

// Round 4
// 730.416 us; speedup vs baseline: 1.0729x; 1.0729x over previous
//
#include <hip/hip_runtime.h>
#include <hip/hip_bf16.h>
#include <math.h>

typedef __attribute__((ext_vector_type(8))) short short8;
typedef __attribute__((ext_vector_type(4))) float f32x4;

__device__ __forceinline__ float bf2f(unsigned short u) {
    union { unsigned int i; float f; } c; c.i = ((unsigned int)u) << 16; return c.f;
}
__device__ __forceinline__ unsigned short f2bf(float f) {
    union { float f; unsigned int i; } c; c.f = f;
    unsigned int i = c.i;
    unsigned int r = (i + 0x7FFFu + ((i >> 16) & 1u)) >> 16;
    return (unsigned short)r;
}
__device__ __forceinline__ float ldf(const float* p, size_t i) { return p[i]; }
__device__ __forceinline__ float ldf(const unsigned short* p, size_t i) { return bf2f(p[i]); }
__device__ __forceinline__ void stf(float* p, size_t i, float v) { p[i] = v; }
__device__ __forceinline__ void stf(unsigned short* p, size_t i, float v) { p[i] = f2bf(v); }

__device__ __forceinline__ void glds16(const unsigned short* g, unsigned short* l) {
    __builtin_amdgcn_global_load_lds(
        (const __attribute__((address_space(1))) unsigned int*)g,
        (__attribute__((address_space(3))) unsigned int*)l, 16, 0, 0);
}

// ---------------- LayerNorm (fp32 input) -> bf16 output ----------------
__global__ __launch_bounds__(256) void ln_f32_kernel(
    const float* __restrict__ x, const float* __restrict__ g,
    const float* __restrict__ b, unsigned short* __restrict__ out) {
    const int row = blockIdx.x;
    const int t = threadIdx.x;
    const float* xr = x + (size_t)row * 1024;
    float4 raw = ((const float4*)xr)[t];
    float v0 = raw.x, v1 = raw.y, v2 = raw.z, v3 = raw.w;
    float s = v0 + v1 + v2 + v3;
    float ss = v0 * v0 + v1 * v1 + v2 * v2 + v3 * v3;
    for (int off = 32; off > 0; off >>= 1) {
        s += __shfl_down(s, off);
        ss += __shfl_down(ss, off);
    }
    __shared__ float red[8];
    __shared__ float stat[2];
    const int wave = t >> 6, lane = t & 63;
    if (lane == 0) { red[wave] = s; red[4 + wave] = ss; }
    __syncthreads();
    if (t == 0) {
        float st = red[0] + red[1] + red[2] + red[3];
        float sst = red[4] + red[5] + red[6] + red[7];
        float mu = st * (1.0f / 1024.0f);
        float var = sst * (1.0f / 1024.0f) - mu * mu;
        stat[0] = mu; stat[1] = rsqrtf(var + 1e-5f);
    }
    __syncthreads();
    const float mu = stat[0], rstd = stat[1];
    float4 gr = ((const float4*)g)[t];
    float4 br = ((const float4*)b)[t];
    ushort4 o;
    o.x = f2bf((v0 - mu) * rstd * gr.x + br.x);
    o.y = f2bf((v1 - mu) * rstd * gr.y + br.y);
    o.z = f2bf((v2 - mu) * rstd * gr.z + br.z);
    o.w = f2bf((v3 - mu) * rstd * gr.w + br.w);
    ((ushort4*)(out + (size_t)row * 1024))[t] = o;
}

// ---------------- LayerNorm (bf16 input) -> bf16 output ----------------
__global__ __launch_bounds__(256) void ln_bf16_kernel(
    const unsigned short* __restrict__ x, const float* __restrict__ g,
    const float* __restrict__ b, unsigned short* __restrict__ out) {
    const int row = blockIdx.x;
    const int t = threadIdx.x;
    const unsigned short* xr = x + (size_t)row * 1024;
    ushort4 raw = ((const ushort4*)xr)[t];
    float v0 = bf2f(raw.x), v1 = bf2f(raw.y), v2 = bf2f(raw.z), v3 = bf2f(raw.w);
    float s = v0 + v1 + v2 + v3;
    float ss = v0 * v0 + v1 * v1 + v2 * v2 + v3 * v3;
    for (int off = 32; off > 0; off >>= 1) {
        s += __shfl_down(s, off);
        ss += __shfl_down(ss, off);
    }
    __shared__ float red[8];
    __shared__ float stat[2];
    const int wave = t >> 6, lane = t & 63;
    if (lane == 0) { red[wave] = s; red[4 + wave] = ss; }
    __syncthreads();
    if (t == 0) {
        float st = red[0] + red[1] + red[2] + red[3];
        float sst = red[4] + red[5] + red[6] + red[7];
        float mu = st * (1.0f / 1024.0f);
        float var = sst * (1.0f / 1024.0f) - mu * mu;
        stat[0] = mu; stat[1] = rsqrtf(var + 1e-5f);
    }
    __syncthreads();
    const float mu = stat[0], rstd = stat[1];
    float4 gr = ((const float4*)g)[t];
    float4 br = ((const float4*)b)[t];
    ushort4 o;
    o.x = f2bf((v0 - mu) * rstd * gr.x + br.x);
    o.y = f2bf((v1 - mu) * rstd * gr.y + br.y);
    o.z = f2bf((v2 - mu) * rstd * gr.z + br.z);
    o.w = f2bf((v3 - mu) * rstd * gr.w + br.w);
    ((ushort4*)(out + (size_t)row * 1024))[t] = o;
}

// ---------------- Transpose+cast: fp32 in[R][C] -> bf16 out[C][R] ----------------
__global__ __launch_bounds__(256) void transpose_cast_kernel(
    const float* __restrict__ in, unsigned short* __restrict__ out, int R, int C) {
    __shared__ unsigned short tile[32][33];
    const int bx = blockIdx.x * 32, by = blockIdx.y * 32;
    const int tx = threadIdx.x & 31, ty = threadIdx.x >> 5;
    for (int i = 0; i < 32; i += 8)
        tile[ty + i][tx] = f2bf(in[(size_t)(by + ty + i) * C + bx + tx]);
    __syncthreads();
    for (int i = 0; i < 32; i += 8)
        out[(size_t)(bx + ty + i) * R + by + tx] = tile[tx][ty + i];
}

// ---------------- GEMM: C[M,N] = A[M,K] * Bt[N,K]^T + bias, fused epilogues ----
// m97 structure: 128x128 tile, BK=32, 4 waves (2x2), 16x16x32 bf16 MFMA,
// global_load_lds width=16 staging.
enum { EPI_QKV = 0, EPI_RES = 1, EPI_GELU = 2 };

template <int EPI, typename RT, typename OT>
__global__ __launch_bounds__(256) void gemm_bt(
    const unsigned short* __restrict__ A, const unsigned short* __restrict__ Bt,
    const float* __restrict__ bias, const RT* __restrict__ res,
    OT* __restrict__ o0, unsigned short* __restrict__ o1,
    unsigned short* __restrict__ o2, int M, int N, int K) {
    __shared__ __align__(16) unsigned short As[128 * 32];
    __shared__ __align__(16) unsigned short Bs[128 * 32];
    const int t = threadIdx.x;
    const int wave = t >> 6, lane = t & 63;
    const int lr = lane & 15, lq = lane >> 4;
    const int wm = (wave >> 1) * 64, wn = (wave & 1) * 64;
    const int m0 = blockIdx.y * 128, n0 = blockIdx.x * 128;
    f32x4 acc[4][4] = {};
    const int arow = t >> 2, acol = (t & 3) << 3;
    const unsigned short* ag = A + (size_t)(m0 + arow) * K + acol;
    const unsigned short* bg = Bt + (size_t)(n0 + arow) * K + acol;
    const size_t rstride = (size_t)64 * K;
    for (int k0 = 0; k0 < K; k0 += 32) {
        glds16(ag + k0, As + t * 8);
        glds16(ag + rstride + k0, As + 2048 + t * 8);
        glds16(bg + k0, Bs + t * 8);
        glds16(bg + rstride + k0, Bs + 2048 + t * 8);
        __syncthreads();
        short8 af[4], bfr[4];
#pragma unroll
        for (int i = 0; i < 4; i++) af[i] = *(const short8*)(As + (wm + i * 16 + lr) * 32 + lq * 8);
#pragma unroll
        for (int i = 0; i < 4; i++) bfr[i] = *(const short8*)(Bs + (wn + i * 16 + lr) * 32 + lq * 8);
#pragma unroll
        for (int mi = 0; mi < 4; mi++)
#pragma unroll
            for (int ni = 0; ni < 4; ni++)
                acc[mi][ni] = __builtin_amdgcn_mfma_f32_16x16x32_bf16(af[mi], bfr[ni], acc[mi][ni], 0, 0, 0);
        __syncthreads();
    }
#pragma unroll
    for (int ni = 0; ni < 4; ni++) {
        const int col = n0 + wn + ni * 16 + lr;
        const float bv = bias[col];
#pragma unroll
        for (int mi = 0; mi < 4; mi++) {
#pragma unroll
            for (int r = 0; r < 4; r++) {
                const int row = m0 + wm + mi * 16 + lq * 4 + r;
                float val = acc[mi][ni][r] + bv;
                if (EPI == EPI_QKV) {
                    const int which = col >> 10, rem = col & 1023;
                    const int hn = rem >> 6, d = rem & 63;
                    const int bb = row >> 11, s = row & 2047;
                    const size_t bh = (size_t)(bb * 16 + hn);
                    if (which == 0) stf((unsigned short*)o0, (bh * 2048 + s) * 64 + d, val);
                    else if (which == 1) o1[(bh * 2048 + s) * 64 + d] = f2bf(val);
                    else o2[(bh * 64 + d) * 2048 + s] = f2bf(val);
                } else if (EPI == EPI_RES) {
                    val += ldf(res, (size_t)row * N + col);
                    stf(o0, (size_t)row * N + col, val);
                } else {  // EPI_GELU: exact gelu
                    val = 0.5f * val * (1.0f + erff(val * 0.70710678118654752f));
                    stf(o0, (size_t)row * N + col, val);
                }
            }
        }
    }
}

// ---------------- Flash attention v2, causal. Hd=64, S=2048, BH=64 ----------------
// 128 q-rows per block (wave owns 32 rows = 2 frags); LDS rows padded to 68 shorts;
// 2 barriers/iter; wave-uniform skip of fully-masked k-tiles.
// q,k: [BH, S, 64]; vt: [BH, 64, S]; out: [B, S, 1024] bf16
__global__ __launch_bounds__(256) void attn_kernel(
    const unsigned short* __restrict__ qb, const unsigned short* __restrict__ kb,
    const unsigned short* __restrict__ vtb, unsigned short* __restrict__ aout) {
    const int bx = blockIdx.x;
    const int qblk = (bx & 1) ? (15 - (bx >> 1)) : (bx >> 1);  // light/heavy interleave
    const int bh = blockIdx.y;
    const int bidx = bh >> 4, h = bh & 15;
    const int t = threadIdx.x, wave = t >> 6, lane = t & 63;
    const int lr = lane & 15, lq = lane >> 4;
    __shared__ __align__(16) unsigned short Ks[64 * 68];
    __shared__ __align__(16) unsigned short Vs[64 * 68];
    __shared__ __align__(16) unsigned short Ps[4][32 * 68];

    const unsigned short* qbase = qb + ((size_t)bh * 2048 + qblk * 128 + wave * 32) * 64;
    short8 qf[2][2];
#pragma unroll
    for (int f = 0; f < 2; f++)
#pragma unroll
        for (int c = 0; c < 2; c++)
            qf[f][c] = *(const short8*)(qbase + (f * 16 + lr) * 64 + c * 32 + lq * 8);

    f32x4 acc[2][4] = {};
    float m_i[2][4], l_i[2][4];
#pragma unroll
    for (int f = 0; f < 2; f++)
#pragma unroll
        for (int r = 0; r < 4; r++) { m_i[f][r] = -1e30f; l_i[f][r] = 0.0f; }

    const unsigned short* kbase = kb + (size_t)bh * 2048 * 64;
    const unsigned short* vbase = vtb + (size_t)bh * 64 * 2048;
    const int srow = t >> 3, scol = (t & 7) * 8;
    const int wave_qmax = qblk * 128 + wave * 32 + 31;
    const int nkt = 2 * (qblk + 1);
    for (int kt = 0; kt < nkt; kt++) {
        const unsigned short* kg = kbase + kt * 4096;
        short8 kr0 = *(const short8*)(kg + t * 8);
        short8 kr1 = *(const short8*)(kg + 2048 + t * 8);
        short8 vr0 = *(const short8*)(vbase + (size_t)srow * 2048 + kt * 64 + scol);
        short8 vr1 = *(const short8*)(vbase + (size_t)(32 + srow) * 2048 + kt * 64 + scol);
        __syncthreads();  // all waves done reading previous Ks/Vs
        *(short8*)(Ks + srow * 68 + scol) = kr0;
        *(short8*)(Ks + (32 + srow) * 68 + scol) = kr1;
        *(short8*)(Vs + srow * 68 + scol) = vr0;
        *(short8*)(Vs + (32 + srow) * 68 + scol) = vr1;
        __syncthreads();
        if (kt * 64 <= wave_qmax) {  // wave-uniform; barriers stay outside
            // S = Q K^T
            f32x4 sa[2][4];
#pragma unroll
            for (int ni = 0; ni < 4; ni++) {
                short8 kf0 = *(const short8*)(Ks + (ni * 16 + lr) * 68 + lq * 8);
                short8 kf1 = *(const short8*)(Ks + (ni * 16 + lr) * 68 + 32 + lq * 8);
#pragma unroll
                for (int f = 0; f < 2; f++) {
                    f32x4 z = {};
                    z = __builtin_amdgcn_mfma_f32_16x16x32_bf16(qf[f][0], kf0, z, 0, 0, 0);
                    sa[f][ni] = __builtin_amdgcn_mfma_f32_16x16x32_bf16(qf[f][1], kf1, z, 0, 0, 0);
                }
            }
            // online softmax per fragment
#pragma unroll
            for (int f = 0; f < 2; f++) {
                const int qrow0 = qblk * 128 + wave * 32 + f * 16 + lq * 4;
                float mcur[4] = {-1e30f, -1e30f, -1e30f, -1e30f};
#pragma unroll
                for (int ni = 0; ni < 4; ni++) {
                    const int kcol = kt * 64 + ni * 16 + lr;
#pragma unroll
                    for (int r = 0; r < 4; r++) {
                        float sv = sa[f][ni][r] * 0.125f;
                        if (kcol > qrow0 + r) sv = -1e30f;
                        sa[f][ni][r] = sv;
                        mcur[r] = fmaxf(mcur[r], sv);
                    }
                }
                float alpha[4], rsum[4];
#pragma unroll
                for (int r = 0; r < 4; r++) {
#pragma unroll
                    for (int off = 1; off < 16; off <<= 1) mcur[r] = fmaxf(mcur[r], __shfl_xor(mcur[r], off));
                    const float mn = fmaxf(m_i[f][r], mcur[r]);
                    alpha[r] = __expf(m_i[f][r] - mn);
                    m_i[f][r] = mn;
                    rsum[r] = 0.0f;
                }
#pragma unroll
                for (int ni = 0; ni < 4; ni++)
#pragma unroll
                    for (int r = 0; r < 4; r++) {
                        const float p = __expf(sa[f][ni][r] - m_i[f][r]);
                        Ps[wave][(f * 16 + lq * 4 + r) * 68 + ni * 16 + lr] = f2bf(p);
                        rsum[r] += p;
                    }
#pragma unroll
                for (int r = 0; r < 4; r++) {
#pragma unroll
                    for (int off = 1; off < 16; off <<= 1) rsum[r] += __shfl_xor(rsum[r], off);
                    l_i[f][r] = l_i[f][r] * alpha[r] + rsum[r];
#pragma unroll
                    for (int ni = 0; ni < 4; ni++) acc[f][ni][r] *= alpha[r];
                }
            }
            // O += P V  (Ps per-wave: no barrier needed; compiler inserts lgkmcnt)
            short8 pf[2][2];
#pragma unroll
            for (int f = 0; f < 2; f++)
#pragma unroll
                for (int c = 0; c < 2; c++)
                    pf[f][c] = *(const short8*)(&Ps[wave][(f * 16 + lr) * 68 + c * 32 + lq * 8]);
#pragma unroll
            for (int ni = 0; ni < 4; ni++) {
                short8 vf0 = *(const short8*)(Vs + (ni * 16 + lr) * 68 + lq * 8);
                short8 vf1 = *(const short8*)(Vs + (ni * 16 + lr) * 68 + 32 + lq * 8);
#pragma unroll
                for (int f = 0; f < 2; f++) {
                    acc[f][ni] = __builtin_amdgcn_mfma_f32_16x16x32_bf16(pf[f][0], vf0, acc[f][ni], 0, 0, 0);
                    acc[f][ni] = __builtin_amdgcn_mfma_f32_16x16x32_bf16(pf[f][1], vf1, acc[f][ni], 0, 0, 0);
                }
            }
        }
    }
#pragma unroll
    for (int f = 0; f < 2; f++)
#pragma unroll
        for (int ni = 0; ni < 4; ni++)
#pragma unroll
            for (int r = 0; r < 4; r++) {
                const int q = qblk * 128 + wave * 32 + f * 16 + lq * 4 + r;
                const size_t token = (size_t)bidx * 2048 + q;
                aout[token * 1024 + h * 64 + ni * 16 + lr] = f2bf(acc[f][ni][r] / l_i[f][r]);
            }
}

// ---------------- launch ----------------
extern "C" void kernel_launch(void* const* d_in, const int* in_sizes, int n_in,
                              void* d_out, int out_size, void* d_ws, size_t ws_size,
                              hipStream_t stream) {
    const float* x      = (const float*)d_in[0];
    const float* qkv_w  = (const float*)d_in[1];
    const float* qkv_b  = (const float*)d_in[2];
    const float* out_w  = (const float*)d_in[3];
    const float* out_b  = (const float*)d_in[4];
    const float* ffn1_w = (const float*)d_in[5];
    const float* ffn1_b = (const float*)d_in[6];
    const float* ffn2_w = (const float*)d_in[7];
    const float* ffn2_b = (const float*)d_in[8];
    const float* ln1_g  = (const float*)d_in[9];
    const float* ln1_b  = (const float*)d_in[10];
    const float* ln2_g  = (const float*)d_in[11];
    const float* ln2_b  = (const float*)d_in[12];
    float* out = (float*)d_out;
    char* W = (char*)d_ws;

    unsigned short* normed = (unsigned short*)(W);
    unsigned short* x1     = (unsigned short*)(W + 16777216);
    unsigned short* qbuf   = (unsigned short*)(W + 33554432);
    unsigned short* kbuf   = (unsigned short*)(W + 50331648);
    unsigned short* vbuf   = (unsigned short*)(W + 67108864);
    unsigned short* attnb  = (unsigned short*)(W + 83886080);
    unsigned short* hff    = (unsigned short*)(W + 33554432);  // reuses q/k/v/attn (dead)
    unsigned short* qkv_wt = (unsigned short*)(W + 100663296);
    unsigned short* out_wt = (unsigned short*)(W + 106954752);
    unsigned short* f1_wt  = (unsigned short*)(W + 109051904);
    unsigned short* f2_wt  = (unsigned short*)(W + 117440512);

    transpose_cast_kernel<<<dim3(3072 / 32, 1024 / 32), 256, 0, stream>>>(qkv_w, qkv_wt, 1024, 3072);
    transpose_cast_kernel<<<dim3(1024 / 32, 1024 / 32), 256, 0, stream>>>(out_w, out_wt, 1024, 1024);
    transpose_cast_kernel<<<dim3(4096 / 32, 1024 / 32), 256, 0, stream>>>(ffn1_w, f1_wt, 1024, 4096);
    transpose_cast_kernel<<<dim3(1024 / 32, 4096 / 32), 256, 0, stream>>>(ffn2_w, f2_wt, 4096, 1024);

    ln_f32_kernel<<<dim3(8192), 256, 0, stream>>>(x, ln1_g, ln1_b, normed);
    gemm_bt<EPI_QKV, float, unsigned short><<<dim3(3072 / 128, 8192 / 128), 256, 0, stream>>>(
        normed, qkv_wt, qkv_b, nullptr, qbuf, kbuf, vbuf, 8192, 3072, 1024);
    attn_kernel<<<dim3(16, 64), 256, 0, stream>>>(qbuf, kbuf, vbuf, attnb);
    gemm_bt<EPI_RES, float, unsigned short><<<dim3(1024 / 128, 8192 / 128), 256, 0, stream>>>(
        attnb, out_wt, out_b, x, x1, nullptr, nullptr, 8192, 1024, 1024);
    ln_bf16_kernel<<<dim3(8192), 256, 0, stream>>>(x1, ln2_g, ln2_b, normed);
    gemm_bt<EPI_GELU, float, unsigned short><<<dim3(4096 / 128, 8192 / 128), 256, 0, stream>>>(
        normed, f1_wt, ffn1_b, nullptr, hff, nullptr, nullptr, 8192, 4096, 1024);
    gemm_bt<EPI_RES, unsigned short, float><<<dim3(1024 / 128, 8192 / 128), 256, 0, stream>>>(
        hff, f2_wt, ffn2_b, x1, out, nullptr, nullptr, 8192, 1024, 4096);
}

// Round 6
// 692.868 us; speedup vs baseline: 1.1310x; 1.0542x over previous
//
#include <hip/hip_runtime.h>
#include <hip/hip_bf16.h>
#include <math.h>

typedef __attribute__((ext_vector_type(8))) short short8;
typedef __attribute__((ext_vector_type(4))) float f32x4;

__device__ __forceinline__ float bf2f(unsigned short u) {
    union { unsigned int i; float f; } c; c.i = ((unsigned int)u) << 16; return c.f;
}
__device__ __forceinline__ unsigned short f2bf(float f) {
    union { float f; unsigned int i; } c; c.f = f;
    unsigned int i = c.i;
    unsigned int r = (i + 0x7FFFu + ((i >> 16) & 1u)) >> 16;
    return (unsigned short)r;
}
__device__ __forceinline__ float ldf(const float* p, size_t i) { return p[i]; }
__device__ __forceinline__ float ldf(const unsigned short* p, size_t i) { return bf2f(p[i]); }
__device__ __forceinline__ void stf(float* p, size_t i, float v) { p[i] = v; }
__device__ __forceinline__ void stf(unsigned short* p, size_t i, float v) { p[i] = f2bf(v); }
__device__ __forceinline__ float fexp2(float x) { return __builtin_amdgcn_exp2f(x); }

__device__ __forceinline__ void glds16(const unsigned short* g, unsigned short* l) {
    __builtin_amdgcn_global_load_lds(
        (const __attribute__((address_space(1))) unsigned int*)g,
        (__attribute__((address_space(3))) unsigned int*)l, 16, 0, 0);
}

// ---------------- LayerNorm (fp32 input) -> bf16 output ----------------
__global__ __launch_bounds__(256) void ln_f32_kernel(
    const float* __restrict__ x, const float* __restrict__ g,
    const float* __restrict__ b, unsigned short* __restrict__ out) {
    const int row = blockIdx.x;
    const int t = threadIdx.x;
    const float* xr = x + (size_t)row * 1024;
    float4 raw = ((const float4*)xr)[t];
    float v0 = raw.x, v1 = raw.y, v2 = raw.z, v3 = raw.w;
    float s = v0 + v1 + v2 + v3;
    float ss = v0 * v0 + v1 * v1 + v2 * v2 + v3 * v3;
    for (int off = 32; off > 0; off >>= 1) {
        s += __shfl_down(s, off);
        ss += __shfl_down(ss, off);
    }
    __shared__ float red[8];
    __shared__ float stat[2];
    const int wave = t >> 6, lane = t & 63;
    if (lane == 0) { red[wave] = s; red[4 + wave] = ss; }
    __syncthreads();
    if (t == 0) {
        float st = red[0] + red[1] + red[2] + red[3];
        float sst = red[4] + red[5] + red[6] + red[7];
        float mu = st * (1.0f / 1024.0f);
        float var = sst * (1.0f / 1024.0f) - mu * mu;
        stat[0] = mu; stat[1] = rsqrtf(var + 1e-5f);
    }
    __syncthreads();
    const float mu = stat[0], rstd = stat[1];
    float4 gr = ((const float4*)g)[t];
    float4 br = ((const float4*)b)[t];
    ushort4 o;
    o.x = f2bf((v0 - mu) * rstd * gr.x + br.x);
    o.y = f2bf((v1 - mu) * rstd * gr.y + br.y);
    o.z = f2bf((v2 - mu) * rstd * gr.z + br.z);
    o.w = f2bf((v3 - mu) * rstd * gr.w + br.w);
    ((ushort4*)(out + (size_t)row * 1024))[t] = o;
}

// ---------------- LayerNorm (bf16 input) -> bf16 output ----------------
__global__ __launch_bounds__(256) void ln_bf16_kernel(
    const unsigned short* __restrict__ x, const float* __restrict__ g,
    const float* __restrict__ b, unsigned short* __restrict__ out) {
    const int row = blockIdx.x;
    const int t = threadIdx.x;
    const unsigned short* xr = x + (size_t)row * 1024;
    ushort4 raw = ((const ushort4*)xr)[t];
    float v0 = bf2f(raw.x), v1 = bf2f(raw.y), v2 = bf2f(raw.z), v3 = bf2f(raw.w);
    float s = v0 + v1 + v2 + v3;
    float ss = v0 * v0 + v1 * v1 + v2 * v2 + v3 * v3;
    for (int off = 32; off > 0; off >>= 1) {
        s += __shfl_down(s, off);
        ss += __shfl_down(ss, off);
    }
    __shared__ float red[8];
    __shared__ float stat[2];
    const int wave = t >> 6, lane = t & 63;
    if (lane == 0) { red[wave] = s; red[4 + wave] = ss; }
    __syncthreads();
    if (t == 0) {
        float st = red[0] + red[1] + red[2] + red[3];
        float sst = red[4] + red[5] + red[6] + red[7];
        float mu = st * (1.0f / 1024.0f);
        float var = sst * (1.0f / 1024.0f) - mu * mu;
        stat[0] = mu; stat[1] = rsqrtf(var + 1e-5f);
    }
    __syncthreads();
    const float mu = stat[0], rstd = stat[1];
    float4 gr = ((const float4*)g)[t];
    float4 br = ((const float4*)b)[t];
    ushort4 o;
    o.x = f2bf((v0 - mu) * rstd * gr.x + br.x);
    o.y = f2bf((v1 - mu) * rstd * gr.y + br.y);
    o.z = f2bf((v2 - mu) * rstd * gr.z + br.z);
    o.w = f2bf((v3 - mu) * rstd * gr.w + br.w);
    ((ushort4*)(out + (size_t)row * 1024))[t] = o;
}

// ---------------- Transpose+cast: fp32 in[R][C] -> bf16 out[C][R] ----------------
__global__ __launch_bounds__(256) void transpose_cast_kernel(
    const float* __restrict__ in, unsigned short* __restrict__ out, int R, int C) {
    __shared__ unsigned short tile[32][33];
    const int bx = blockIdx.x * 32, by = blockIdx.y * 32;
    const int tx = threadIdx.x & 31, ty = threadIdx.x >> 5;
    for (int i = 0; i < 32; i += 8)
        tile[ty + i][tx] = f2bf(in[(size_t)(by + ty + i) * C + bx + tx]);
    __syncthreads();
    for (int i = 0; i < 32; i += 8)
        out[(size_t)(bx + ty + i) * R + by + tx] = tile[tx][ty + i];
}

// ---------------- GEMM: C[M,N] = A[M,K] * Bt[N,K]^T + bias, fused epilogues ----
// 128xBN tile, BK=32, 4 waves, 16x16x32 bf16 MFMA, global_load_lds staging.
// BN=128 for wide GEMMs; BN=64 doubles block count for N=1024 GEMMs (grid fill).
enum { EPI_QKV = 0, EPI_RES = 1, EPI_GELU = 2 };

template <int EPI, int BN, typename RT, typename OT>
__global__ __launch_bounds__(256) void gemm_bt(
    const unsigned short* __restrict__ A, const unsigned short* __restrict__ Bt,
    const float* __restrict__ bias, const RT* __restrict__ res,
    OT* __restrict__ o0, unsigned short* __restrict__ o1,
    unsigned short* __restrict__ o2, int M, int N, int K) {
    __shared__ __align__(16) unsigned short As[128 * 32];
    __shared__ __align__(16) unsigned short Bs[BN * 32];
    constexpr int NF = BN / 32;  // n-fragments per wave
    const int t = threadIdx.x;
    const int wave = t >> 6, lane = t & 63;
    const int lr = lane & 15, lq = lane >> 4;
    const int wm = (wave >> 1) * 64, wn = (wave & 1) * (BN / 2);
    const int m0 = blockIdx.y * 128, n0 = blockIdx.x * BN;
    f32x4 acc[4][NF] = {};
    const int arow = t >> 2, acol = (t & 3) << 3;
    const unsigned short* ag = A + (size_t)(m0 + arow) * K + acol;
    const unsigned short* bg = Bt + (size_t)(n0 + arow) * K + acol;
    const size_t rstride = (size_t)64 * K;
    for (int k0 = 0; k0 < K; k0 += 32) {
        glds16(ag + k0, As + t * 8);
        glds16(ag + rstride + k0, As + 2048 + t * 8);
        glds16(bg + k0, Bs + t * 8);
        if (BN == 128) glds16(bg + rstride + k0, Bs + 2048 + t * 8);
        __syncthreads();
        short8 af[4], bfr[NF];
#pragma unroll
        for (int i = 0; i < 4; i++) af[i] = *(const short8*)(As + (wm + i * 16 + lr) * 32 + lq * 8);
#pragma unroll
        for (int i = 0; i < NF; i++) bfr[i] = *(const short8*)(Bs + (wn + i * 16 + lr) * 32 + lq * 8);
#pragma unroll
        for (int mi = 0; mi < 4; mi++)
#pragma unroll
            for (int ni = 0; ni < NF; ni++)
                acc[mi][ni] = __builtin_amdgcn_mfma_f32_16x16x32_bf16(af[mi], bfr[ni], acc[mi][ni], 0, 0, 0);
        __syncthreads();
    }
#pragma unroll
    for (int ni = 0; ni < NF; ni++) {
        const int col = n0 + wn + ni * 16 + lr;
        const float bv = bias[col];
#pragma unroll
        for (int mi = 0; mi < 4; mi++) {
#pragma unroll
            for (int r = 0; r < 4; r++) {
                const int row = m0 + wm + mi * 16 + lq * 4 + r;
                float val = acc[mi][ni][r] + bv;
                if (EPI == EPI_QKV) {
                    const int which = col >> 10, rem = col & 1023;
                    const int hn = rem >> 6, d = rem & 63;
                    const int bb = row >> 11, s = row & 2047;
                    const size_t bh = (size_t)(bb * 16 + hn);
                    if (which == 0) stf((unsigned short*)o0, (bh * 2048 + s) * 64 + d, val);
                    else if (which == 1) o1[(bh * 2048 + s) * 64 + d] = f2bf(val);
                    else o2[(bh * 64 + d) * 2048 + s] = f2bf(val);
                } else if (EPI == EPI_RES) {
                    val += ldf(res, (size_t)row * N + col);
                    stf(o0, (size_t)row * N + col, val);
                } else {  // EPI_GELU: exact gelu
                    val = 0.5f * val * (1.0f + erff(val * 0.70710678118654752f));
                    stf(o0, (size_t)row * N + col, val);
                }
            }
        }
    }
}

// ---------------- Flash attention v3, causal. Hd=64, S=2048, BH=64 ----------------
// Paired q-tiles per block (bx and 15-bx, sequential) -> uniform 34 k-tiles/block.
// K/V software-pipelined (preload next tile into regs during compute).
// exp2-domain softmax (scale folded into Q). Wave-uniform mask skip.
__global__ __launch_bounds__(256) void attn_kernel(
    const unsigned short* __restrict__ qb, const unsigned short* __restrict__ kb,
    const unsigned short* __restrict__ vtb, unsigned short* __restrict__ aout) {
    const int bx = blockIdx.x;  // 0..7
    const int bh = blockIdx.y;
    const int bidx = bh >> 4, h = bh & 15;
    const int t = threadIdx.x, wave = t >> 6, lane = t & 63;
    const int lr = lane & 15, lq = lane >> 4;
    __shared__ __align__(16) unsigned short Ks[64 * 68];
    __shared__ __align__(16) unsigned short Vs[64 * 68];
    __shared__ __align__(16) unsigned short Ps[4][32 * 68];
    const unsigned short* kbase = kb + (size_t)bh * 2048 * 64;
    const unsigned short* vbase = vtb + (size_t)bh * 64 * 2048;
    const int srow = t >> 3, scol = (t & 7) * 8;
    const float kQScale = 0.125f * 1.44269504088896f;  // fold softmax scale + log2e into Q

    for (int phase = 0; phase < 2; phase++) {
        const int qblk = phase ? (15 - bx) : bx;
        const unsigned short* qbase = qb + ((size_t)bh * 2048 + qblk * 128 + wave * 32) * 64;
        short8 qf[2][2];
#pragma unroll
        for (int f = 0; f < 2; f++)
#pragma unroll
            for (int c = 0; c < 2; c++) {
                short8 raw = *(const short8*)(qbase + (f * 16 + lr) * 64 + c * 32 + lq * 8);
                short8 sc;
#pragma unroll
                for (int j = 0; j < 8; j++)
                    sc[j] = (short)f2bf(bf2f((unsigned short)raw[j]) * kQScale);
                qf[f][c] = sc;
            }
        f32x4 acc[2][4] = {};
        float m_i[2][4], l_i[2][4];
#pragma unroll
        for (int f = 0; f < 2; f++)
#pragma unroll
            for (int r = 0; r < 4; r++) { m_i[f][r] = -1e30f; l_i[f][r] = 0.0f; }
        const int wave_q0 = qblk * 128 + wave * 32;
        const int nkt = 2 * (qblk + 1);
        // preload tile 0
        short8 kr0 = *(const short8*)(kbase + t * 8);
        short8 kr1 = *(const short8*)(kbase + 2048 + t * 8);
        short8 vr0 = *(const short8*)(vbase + (size_t)srow * 2048 + scol);
        short8 vr1 = *(const short8*)(vbase + (size_t)(32 + srow) * 2048 + scol);
        for (int kt = 0; kt < nkt; kt++) {
            __syncthreads();  // all waves done reading previous Ks/Vs
            *(short8*)(Ks + srow * 68 + scol) = kr0;
            *(short8*)(Ks + (32 + srow) * 68 + scol) = kr1;
            *(short8*)(Vs + srow * 68 + scol) = vr0;
            *(short8*)(Vs + (32 + srow) * 68 + scol) = vr1;
            __syncthreads();
            if (kt + 1 < nkt) {  // preload next tile: latency hidden behind compute
                const unsigned short* kg = kbase + (kt + 1) * 4096;
                kr0 = *(const short8*)(kg + t * 8);
                kr1 = *(const short8*)(kg + 2048 + t * 8);
                vr0 = *(const short8*)(vbase + (size_t)srow * 2048 + (kt + 1) * 64 + scol);
                vr1 = *(const short8*)(vbase + (size_t)(32 + srow) * 2048 + (kt + 1) * 64 + scol);
            }
            if (kt * 64 <= wave_q0 + 31) {  // wave-uniform; barriers stay outside
                f32x4 sa[2][4];
#pragma unroll
                for (int ni = 0; ni < 4; ni++) {
                    short8 kf0 = *(const short8*)(Ks + (ni * 16 + lr) * 68 + lq * 8);
                    short8 kf1 = *(const short8*)(Ks + (ni * 16 + lr) * 68 + 32 + lq * 8);
#pragma unroll
                    for (int f = 0; f < 2; f++) {
                        f32x4 z = {};
                        z = __builtin_amdgcn_mfma_f32_16x16x32_bf16(qf[f][0], kf0, z, 0, 0, 0);
                        sa[f][ni] = __builtin_amdgcn_mfma_f32_16x16x32_bf16(qf[f][1], kf1, z, 0, 0, 0);
                    }
                }
                const bool needmask = (kt * 64 + 63 > wave_q0);  // wave-uniform
                if (needmask) {
#pragma unroll
                    for (int f = 0; f < 2; f++) {
                        const int qrow0 = wave_q0 + f * 16 + lq * 4;
#pragma unroll
                        for (int ni = 0; ni < 4; ni++) {
                            const int kcol = kt * 64 + ni * 16 + lr;
#pragma unroll
                            for (int r = 0; r < 4; r++)
                                if (kcol > qrow0 + r) sa[f][ni][r] = -1e30f;
                        }
                    }
                }
#pragma unroll
                for (int f = 0; f < 2; f++) {
                    float mcur[4], alpha[4], rsum[4];
#pragma unroll
                    for (int r = 0; r < 4; r++)
                        mcur[r] = fmaxf(fmaxf(sa[f][0][r], sa[f][1][r]), fmaxf(sa[f][2][r], sa[f][3][r]));
#pragma unroll
                    for (int r = 0; r < 4; r++) {
#pragma unroll
                        for (int off = 1; off < 16; off <<= 1) mcur[r] = fmaxf(mcur[r], __shfl_xor(mcur[r], off));
                        const float mn = fmaxf(m_i[f][r], mcur[r]);
                        alpha[r] = fexp2(m_i[f][r] - mn);
                        m_i[f][r] = mn;
                        rsum[r] = 0.0f;
                    }
#pragma unroll
                    for (int ni = 0; ni < 4; ni++)
#pragma unroll
                        for (int r = 0; r < 4; r++) {
                            const float p = fexp2(sa[f][ni][r] - m_i[f][r]);
                            Ps[wave][(f * 16 + lq * 4 + r) * 68 + ni * 16 + lr] = f2bf(p);
                            rsum[r] += p;
                        }
#pragma unroll
                    for (int r = 0; r < 4; r++) {
#pragma unroll
                        for (int off = 1; off < 16; off <<= 1) rsum[r] += __shfl_xor(rsum[r], off);
                        l_i[f][r] = l_i[f][r] * alpha[r] + rsum[r];
#pragma unroll
                        for (int ni = 0; ni < 4; ni++) acc[f][ni][r] *= alpha[r];
                    }
                }
                // O += P V  (Ps per-wave: compiler inserts lgkmcnt, no barrier)
                short8 pf[2][2];
#pragma unroll
                for (int f = 0; f < 2; f++)
#pragma unroll
                    for (int c = 0; c < 2; c++)
                        pf[f][c] = *(const short8*)(&Ps[wave][(f * 16 + lr) * 68 + c * 32 + lq * 8]);
#pragma unroll
                for (int ni = 0; ni < 4; ni++) {
                    short8 vf0 = *(const short8*)(Vs + (ni * 16 + lr) * 68 + lq * 8);
                    short8 vf1 = *(const short8*)(Vs + (ni * 16 + lr) * 68 + 32 + lq * 8);
#pragma unroll
                    for (int f = 0; f < 2; f++) {
                        acc[f][ni] = __builtin_amdgcn_mfma_f32_16x16x32_bf16(pf[f][0], vf0, acc[f][ni], 0, 0, 0);
                        acc[f][ni] = __builtin_amdgcn_mfma_f32_16x16x32_bf16(pf[f][1], vf1, acc[f][ni], 0, 0, 0);
                    }
                }
            }
        }
#pragma unroll
        for (int f = 0; f < 2; f++)
#pragma unroll
            for (int r = 0; r < 4; r++) {
                const float rinv = 1.0f / l_i[f][r];
                const int q = qblk * 128 + wave * 32 + f * 16 + lq * 4 + r;
                const size_t token = (size_t)bidx * 2048 + q;
#pragma unroll
                for (int ni = 0; ni < 4; ni++)
                    aout[token * 1024 + h * 64 + ni * 16 + lr] = f2bf(acc[f][ni][r] * rinv);
            }
    }
}

// ---------------- launch ----------------
extern "C" void kernel_launch(void* const* d_in, const int* in_sizes, int n_in,
                              void* d_out, int out_size, void* d_ws, size_t ws_size,
                              hipStream_t stream) {
    const float* x      = (const float*)d_in[0];
    const float* qkv_w  = (const float*)d_in[1];
    const float* qkv_b  = (const float*)d_in[2];
    const float* out_w  = (const float*)d_in[3];
    const float* out_b  = (const float*)d_in[4];
    const float* ffn1_w = (const float*)d_in[5];
    const float* ffn1_b = (const float*)d_in[6];
    const float* ffn2_w = (const float*)d_in[7];
    const float* ffn2_b = (const float*)d_in[8];
    const float* ln1_g  = (const float*)d_in[9];
    const float* ln1_b  = (const float*)d_in[10];
    const float* ln2_g  = (const float*)d_in[11];
    const float* ln2_b  = (const float*)d_in[12];
    float* out = (float*)d_out;
    char* W = (char*)d_ws;

    unsigned short* normed = (unsigned short*)(W);
    unsigned short* x1     = (unsigned short*)(W + 16777216);
    unsigned short* qbuf   = (unsigned short*)(W + 33554432);
    unsigned short* kbuf   = (unsigned short*)(W + 50331648);
    unsigned short* vbuf   = (unsigned short*)(W + 67108864);
    unsigned short* attnb  = (unsigned short*)(W + 83886080);
    unsigned short* hff    = (unsigned short*)(W + 33554432);  // reuses q/k/v/attn (dead)
    unsigned short* qkv_wt = (unsigned short*)(W + 100663296);
    unsigned short* out_wt = (unsigned short*)(W + 106954752);
    unsigned short* f1_wt  = (unsigned short*)(W + 109051904);
    unsigned short* f2_wt  = (unsigned short*)(W + 117440512);

    transpose_cast_kernel<<<dim3(3072 / 32, 1024 / 32), 256, 0, stream>>>(qkv_w, qkv_wt, 1024, 3072);
    transpose_cast_kernel<<<dim3(1024 / 32, 1024 / 32), 256, 0, stream>>>(out_w, out_wt, 1024, 1024);
    transpose_cast_kernel<<<dim3(4096 / 32, 1024 / 32), 256, 0, stream>>>(ffn1_w, f1_wt, 1024, 4096);
    transpose_cast_kernel<<<dim3(1024 / 32, 4096 / 32), 256, 0, stream>>>(ffn2_w, f2_wt, 4096, 1024);

    ln_f32_kernel<<<dim3(8192), 256, 0, stream>>>(x, ln1_g, ln1_b, normed);
    gemm_bt<EPI_QKV, 128, float, unsigned short><<<dim3(3072 / 128, 8192 / 128), 256, 0, stream>>>(
        normed, qkv_wt, qkv_b, nullptr, qbuf, kbuf, vbuf, 8192, 3072, 1024);
    attn_kernel<<<dim3(8, 64), 256, 0, stream>>>(qbuf, kbuf, vbuf, attnb);
    gemm_bt<EPI_RES, 64, float, unsigned short><<<dim3(1024 / 64, 8192 / 128), 256, 0, stream>>>(
        attnb, out_wt, out_b, x, x1, nullptr, nullptr, 8192, 1024, 1024);
    ln_bf16_kernel<<<dim3(8192), 256, 0, stream>>>(x1, ln2_g, ln2_b, normed);
    gemm_bt<EPI_GELU, 128, float, unsigned short><<<dim3(4096 / 128, 8192 / 128), 256, 0, stream>>>(
        normed, f1_wt, ffn1_b, nullptr, hff, nullptr, nullptr, 8192, 4096, 1024);
    gemm_bt<EPI_RES, 64, unsigned short, float><<<dim3(1024 / 64, 8192 / 128), 256, 0, stream>>>(
        hff, f2_wt, ffn2_b, x1, out, nullptr, nullptr, 8192, 1024, 4096);
}

// Round 7
// 630.021 us; speedup vs baseline: 1.2439x; 1.0998x over previous
//
#include <hip/hip_runtime.h>
#include <hip/hip_bf16.h>
#include <math.h>

typedef __attribute__((ext_vector_type(8))) short short8;
typedef __attribute__((ext_vector_type(4))) float f32x4;

__device__ __forceinline__ float bf2f(unsigned short u) {
    union { unsigned int i; float f; } c; c.i = ((unsigned int)u) << 16; return c.f;
}
__device__ __forceinline__ unsigned short f2bf(float f) {
    union { float f; unsigned int i; } c; c.f = f;
    unsigned int i = c.i;
    unsigned int r = (i + 0x7FFFu + ((i >> 16) & 1u)) >> 16;
    return (unsigned short)r;
}
__device__ __forceinline__ float ldf(const float* p, size_t i) { return p[i]; }
__device__ __forceinline__ float ldf(const unsigned short* p, size_t i) { return bf2f(p[i]); }
__device__ __forceinline__ void stf(float* p, size_t i, float v) { p[i] = v; }
__device__ __forceinline__ void stf(unsigned short* p, size_t i, float v) { p[i] = f2bf(v); }
__device__ __forceinline__ float fexp2(float x) { return __builtin_amdgcn_exp2f(x); }

// ---------------- LayerNorm (fp32 input) -> bf16 output ----------------
__global__ __launch_bounds__(256) void ln_f32_kernel(
    const float* __restrict__ x, const float* __restrict__ g,
    const float* __restrict__ b, unsigned short* __restrict__ out) {
    const int row = blockIdx.x;
    const int t = threadIdx.x;
    const float* xr = x + (size_t)row * 1024;
    float4 raw = ((const float4*)xr)[t];
    float v0 = raw.x, v1 = raw.y, v2 = raw.z, v3 = raw.w;
    float s = v0 + v1 + v2 + v3;
    float ss = v0 * v0 + v1 * v1 + v2 * v2 + v3 * v3;
    for (int off = 32; off > 0; off >>= 1) {
        s += __shfl_down(s, off);
        ss += __shfl_down(ss, off);
    }
    __shared__ float red[8];
    __shared__ float stat[2];
    const int wave = t >> 6, lane = t & 63;
    if (lane == 0) { red[wave] = s; red[4 + wave] = ss; }
    __syncthreads();
    if (t == 0) {
        float st = red[0] + red[1] + red[2] + red[3];
        float sst = red[4] + red[5] + red[6] + red[7];
        float mu = st * (1.0f / 1024.0f);
        float var = sst * (1.0f / 1024.0f) - mu * mu;
        stat[0] = mu; stat[1] = rsqrtf(var + 1e-5f);
    }
    __syncthreads();
    const float mu = stat[0], rstd = stat[1];
    float4 gr = ((const float4*)g)[t];
    float4 br = ((const float4*)b)[t];
    ushort4 o;
    o.x = f2bf((v0 - mu) * rstd * gr.x + br.x);
    o.y = f2bf((v1 - mu) * rstd * gr.y + br.y);
    o.z = f2bf((v2 - mu) * rstd * gr.z + br.z);
    o.w = f2bf((v3 - mu) * rstd * gr.w + br.w);
    ((ushort4*)(out + (size_t)row * 1024))[t] = o;
}

// ---------------- LayerNorm (bf16 input) -> bf16 output ----------------
__global__ __launch_bounds__(256) void ln_bf16_kernel(
    const unsigned short* __restrict__ x, const float* __restrict__ g,
    const float* __restrict__ b, unsigned short* __restrict__ out) {
    const int row = blockIdx.x;
    const int t = threadIdx.x;
    const unsigned short* xr = x + (size_t)row * 1024;
    ushort4 raw = ((const ushort4*)xr)[t];
    float v0 = bf2f(raw.x), v1 = bf2f(raw.y), v2 = bf2f(raw.z), v3 = bf2f(raw.w);
    float s = v0 + v1 + v2 + v3;
    float ss = v0 * v0 + v1 * v1 + v2 * v2 + v3 * v3;
    for (int off = 32; off > 0; off >>= 1) {
        s += __shfl_down(s, off);
        ss += __shfl_down(ss, off);
    }
    __shared__ float red[8];
    __shared__ float stat[2];
    const int wave = t >> 6, lane = t & 63;
    if (lane == 0) { red[wave] = s; red[4 + wave] = ss; }
    __syncthreads();
    if (t == 0) {
        float st = red[0] + red[1] + red[2] + red[3];
        float sst = red[4] + red[5] + red[6] + red[7];
        float mu = st * (1.0f / 1024.0f);
        float var = sst * (1.0f / 1024.0f) - mu * mu;
        stat[0] = mu; stat[1] = rsqrtf(var + 1e-5f);
    }
    __syncthreads();
    const float mu = stat[0], rstd = stat[1];
    float4 gr = ((const float4*)g)[t];
    float4 br = ((const float4*)b)[t];
    ushort4 o;
    o.x = f2bf((v0 - mu) * rstd * gr.x + br.x);
    o.y = f2bf((v1 - mu) * rstd * gr.y + br.y);
    o.z = f2bf((v2 - mu) * rstd * gr.z + br.z);
    o.w = f2bf((v3 - mu) * rstd * gr.w + br.w);
    ((ushort4*)(out + (size_t)row * 1024))[t] = o;
}

// ---------------- Transpose+cast: fp32 in[R][C] -> bf16 out[C][R] ----------------
__global__ __launch_bounds__(256) void transpose_cast_kernel(
    const float* __restrict__ in, unsigned short* __restrict__ out, int R, int C) {
    __shared__ unsigned short tile[32][33];
    const int bx = blockIdx.x * 32, by = blockIdx.y * 32;
    const int tx = threadIdx.x & 31, ty = threadIdx.x >> 5;
    for (int i = 0; i < 32; i += 8)
        tile[ty + i][tx] = f2bf(in[(size_t)(by + ty + i) * C + bx + tx]);
    __syncthreads();
    for (int i = 0; i < 32; i += 8)
        out[(size_t)(bx + ty + i) * R + by + tx] = tile[tx][ty + i];
}

// ---------------- GEMM: C[M,N] = A[M,K] * Bt[N,K]^T + bias, fused epilogues ----
// 128x128 tile, BK=32, 4 waves (2x2), 16x16x32 bf16 MFMA.
// Software-pipelined register staging: global loads for k+1 issue before the
// MFMA phase of k (latency overlapped); barriers only drain LDS writes.
// LDS rows padded to 40 shorts (80B): stores and b128 frag reads are <=2-way.
enum { EPI_QKV = 0, EPI_RES = 1, EPI_GELU = 2 };

template <int EPI, typename RT, typename OT>
__global__ __launch_bounds__(256) void gemm_bt(
    const unsigned short* __restrict__ A, const unsigned short* __restrict__ Bt,
    const float* __restrict__ bias, const RT* __restrict__ res,
    OT* __restrict__ o0, unsigned short* __restrict__ o1,
    unsigned short* __restrict__ o2, int M, int N, int K) {
    constexpr int LDW = 40;
    __shared__ __align__(16) unsigned short As[128 * LDW];
    __shared__ __align__(16) unsigned short Bs[128 * LDW];
    const int t = threadIdx.x;
    const int wave = t >> 6, lane = t & 63;
    const int lr = lane & 15, lq = lane >> 4;
    const int wm = (wave >> 1) * 64, wn = (wave & 1) * 64;
    const int m0 = blockIdx.y * 128, n0 = blockIdx.x * 128;
    f32x4 acc[4][4] = {};
    const int arow = t >> 2, acol = (t & 3) << 3;
    const unsigned short* ag = A + (size_t)(m0 + arow) * K + acol;
    const unsigned short* bg = Bt + (size_t)(n0 + arow) * K + acol;
    const size_t rstride = (size_t)64 * K;
    // preload k0 = 0
    short8 a0 = *(const short8*)(ag);
    short8 a1 = *(const short8*)(ag + rstride);
    short8 b0 = *(const short8*)(bg);
    short8 b1 = *(const short8*)(bg + rstride);
    for (int k0 = 0; k0 < K; k0 += 32) {
        __syncthreads();  // previous iteration's fragment reads complete
        *(short8*)(As + arow * LDW + acol) = a0;
        *(short8*)(As + (arow + 64) * LDW + acol) = a1;
        *(short8*)(Bs + arow * LDW + acol) = b0;
        *(short8*)(Bs + (arow + 64) * LDW + acol) = b1;
        __syncthreads();
        if (k0 + 32 < K) {  // issue k+1 loads: latency hides behind MFMA phase
            a0 = *(const short8*)(ag + k0 + 32);
            a1 = *(const short8*)(ag + rstride + k0 + 32);
            b0 = *(const short8*)(bg + k0 + 32);
            b1 = *(const short8*)(bg + rstride + k0 + 32);
        }
        short8 af[4], bfr[4];
#pragma unroll
        for (int i = 0; i < 4; i++) af[i] = *(const short8*)(As + (wm + i * 16 + lr) * LDW + lq * 8);
#pragma unroll
        for (int i = 0; i < 4; i++) bfr[i] = *(const short8*)(Bs + (wn + i * 16 + lr) * LDW + lq * 8);
#pragma unroll
        for (int mi = 0; mi < 4; mi++)
#pragma unroll
            for (int ni = 0; ni < 4; ni++)
                acc[mi][ni] = __builtin_amdgcn_mfma_f32_16x16x32_bf16(af[mi], bfr[ni], acc[mi][ni], 0, 0, 0);
    }
#pragma unroll
    for (int ni = 0; ni < 4; ni++) {
        const int col = n0 + wn + ni * 16 + lr;
        const float bv = bias[col];
#pragma unroll
        for (int mi = 0; mi < 4; mi++) {
#pragma unroll
            for (int r = 0; r < 4; r++) {
                const int row = m0 + wm + mi * 16 + lq * 4 + r;
                float val = acc[mi][ni][r] + bv;
                if (EPI == EPI_QKV) {
                    const int which = col >> 10, rem = col & 1023;
                    const int hn = rem >> 6, d = rem & 63;
                    const int bb = row >> 11, s = row & 2047;
                    const size_t bh = (size_t)(bb * 16 + hn);
                    if (which == 0) stf((unsigned short*)o0, (bh * 2048 + s) * 64 + d, val);
                    else if (which == 1) o1[(bh * 2048 + s) * 64 + d] = f2bf(val);
                    else o2[(bh * 64 + d) * 2048 + s] = f2bf(val);
                } else if (EPI == EPI_RES) {
                    val += ldf(res, (size_t)row * N + col);
                    stf(o0, (size_t)row * N + col, val);
                } else {  // EPI_GELU: exact gelu
                    val = 0.5f * val * (1.0f + erff(val * 0.70710678118654752f));
                    stf(o0, (size_t)row * N + col, val);
                }
            }
        }
    }
}

// ---------------- Flash attention v3, causal. Hd=64, S=2048, BH=64 ----------------
// Paired q-tiles per block (bx and 15-bx, sequential) -> uniform 34 k-tiles/block.
// K/V software-pipelined. exp2-domain softmax. Wave-uniform mask skip.
__global__ __launch_bounds__(256) void attn_kernel(
    const unsigned short* __restrict__ qb, const unsigned short* __restrict__ kb,
    const unsigned short* __restrict__ vtb, unsigned short* __restrict__ aout) {
    const int bx = blockIdx.x;  // 0..7
    const int bh = blockIdx.y;
    const int bidx = bh >> 4, h = bh & 15;
    const int t = threadIdx.x, wave = t >> 6, lane = t & 63;
    const int lr = lane & 15, lq = lane >> 4;
    __shared__ __align__(16) unsigned short Ks[64 * 68];
    __shared__ __align__(16) unsigned short Vs[64 * 68];
    __shared__ __align__(16) unsigned short Ps[4][32 * 68];
    const unsigned short* kbase = kb + (size_t)bh * 2048 * 64;
    const unsigned short* vbase = vtb + (size_t)bh * 64 * 2048;
    const int srow = t >> 3, scol = (t & 7) * 8;
    const float kQScale = 0.125f * 1.44269504088896f;  // softmax scale + log2e into Q

    for (int phase = 0; phase < 2; phase++) {
        const int qblk = phase ? (15 - bx) : bx;
        const unsigned short* qbase = qb + ((size_t)bh * 2048 + qblk * 128 + wave * 32) * 64;
        short8 qf[2][2];
#pragma unroll
        for (int f = 0; f < 2; f++)
#pragma unroll
            for (int c = 0; c < 2; c++) {
                short8 raw = *(const short8*)(qbase + (f * 16 + lr) * 64 + c * 32 + lq * 8);
                short8 sc;
#pragma unroll
                for (int j = 0; j < 8; j++)
                    sc[j] = (short)f2bf(bf2f((unsigned short)raw[j]) * kQScale);
                qf[f][c] = sc;
            }
        f32x4 acc[2][4] = {};
        float m_i[2][4], l_i[2][4];
#pragma unroll
        for (int f = 0; f < 2; f++)
#pragma unroll
            for (int r = 0; r < 4; r++) { m_i[f][r] = -1e30f; l_i[f][r] = 0.0f; }
        const int wave_q0 = qblk * 128 + wave * 32;
        const int nkt = 2 * (qblk + 1);
        short8 kr0 = *(const short8*)(kbase + t * 8);
        short8 kr1 = *(const short8*)(kbase + 2048 + t * 8);
        short8 vr0 = *(const short8*)(vbase + (size_t)srow * 2048 + scol);
        short8 vr1 = *(const short8*)(vbase + (size_t)(32 + srow) * 2048 + scol);
        for (int kt = 0; kt < nkt; kt++) {
            __syncthreads();
            *(short8*)(Ks + srow * 68 + scol) = kr0;
            *(short8*)(Ks + (32 + srow) * 68 + scol) = kr1;
            *(short8*)(Vs + srow * 68 + scol) = vr0;
            *(short8*)(Vs + (32 + srow) * 68 + scol) = vr1;
            __syncthreads();
            if (kt + 1 < nkt) {
                const unsigned short* kg = kbase + (kt + 1) * 4096;
                kr0 = *(const short8*)(kg + t * 8);
                kr1 = *(const short8*)(kg + 2048 + t * 8);
                vr0 = *(const short8*)(vbase + (size_t)srow * 2048 + (kt + 1) * 64 + scol);
                vr1 = *(const short8*)(vbase + (size_t)(32 + srow) * 2048 + (kt + 1) * 64 + scol);
            }
            if (kt * 64 <= wave_q0 + 31) {
                f32x4 sa[2][4];
#pragma unroll
                for (int ni = 0; ni < 4; ni++) {
                    short8 kf0 = *(const short8*)(Ks + (ni * 16 + lr) * 68 + lq * 8);
                    short8 kf1 = *(const short8*)(Ks + (ni * 16 + lr) * 68 + 32 + lq * 8);
#pragma unroll
                    for (int f = 0; f < 2; f++) {
                        f32x4 z = {};
                        z = __builtin_amdgcn_mfma_f32_16x16x32_bf16(qf[f][0], kf0, z, 0, 0, 0);
                        sa[f][ni] = __builtin_amdgcn_mfma_f32_16x16x32_bf16(qf[f][1], kf1, z, 0, 0, 0);
                    }
                }
                const bool needmask = (kt * 64 + 63 > wave_q0);
                if (needmask) {
#pragma unroll
                    for (int f = 0; f < 2; f++) {
                        const int qrow0 = wave_q0 + f * 16 + lq * 4;
#pragma unroll
                        for (int ni = 0; ni < 4; ni++) {
                            const int kcol = kt * 64 + ni * 16 + lr;
#pragma unroll
                            for (int r = 0; r < 4; r++)
                                if (kcol > qrow0 + r) sa[f][ni][r] = -1e30f;
                        }
                    }
                }
#pragma unroll
                for (int f = 0; f < 2; f++) {
                    float mcur[4], alpha[4], rsum[4];
#pragma unroll
                    for (int r = 0; r < 4; r++)
                        mcur[r] = fmaxf(fmaxf(sa[f][0][r], sa[f][1][r]), fmaxf(sa[f][2][r], sa[f][3][r]));
#pragma unroll
                    for (int r = 0; r < 4; r++) {
#pragma unroll
                        for (int off = 1; off < 16; off <<= 1) mcur[r] = fmaxf(mcur[r], __shfl_xor(mcur[r], off));
                        const float mn = fmaxf(m_i[f][r], mcur[r]);
                        alpha[r] = fexp2(m_i[f][r] - mn);
                        m_i[f][r] = mn;
                        rsum[r] = 0.0f;
                    }
#pragma unroll
                    for (int ni = 0; ni < 4; ni++)
#pragma unroll
                        for (int r = 0; r < 4; r++) {
                            const float p = fexp2(sa[f][ni][r] - m_i[f][r]);
                            Ps[wave][(f * 16 + lq * 4 + r) * 68 + ni * 16 + lr] = f2bf(p);
                            rsum[r] += p;
                        }
#pragma unroll
                    for (int r = 0; r < 4; r++) {
#pragma unroll
                        for (int off = 1; off < 16; off <<= 1) rsum[r] += __shfl_xor(rsum[r], off);
                        l_i[f][r] = l_i[f][r] * alpha[r] + rsum[r];
#pragma unroll
                        for (int ni = 0; ni < 4; ni++) acc[f][ni][r] *= alpha[r];
                    }
                }
                short8 pf[2][2];
#pragma unroll
                for (int f = 0; f < 2; f++)
#pragma unroll
                    for (int c = 0; c < 2; c++)
                        pf[f][c] = *(const short8*)(&Ps[wave][(f * 16 + lr) * 68 + c * 32 + lq * 8]);
#pragma unroll
                for (int ni = 0; ni < 4; ni++) {
                    short8 vf0 = *(const short8*)(Vs + (ni * 16 + lr) * 68 + lq * 8);
                    short8 vf1 = *(const short8*)(Vs + (ni * 16 + lr) * 68 + 32 + lq * 8);
#pragma unroll
                    for (int f = 0; f < 2; f++) {
                        acc[f][ni] = __builtin_amdgcn_mfma_f32_16x16x32_bf16(pf[f][0], vf0, acc[f][ni], 0, 0, 0);
                        acc[f][ni] = __builtin_amdgcn_mfma_f32_16x16x32_bf16(pf[f][1], vf1, acc[f][ni], 0, 0, 0);
                    }
                }
            }
        }
#pragma unroll
        for (int f = 0; f < 2; f++)
#pragma unroll
            for (int r = 0; r < 4; r++) {
                const float rinv = 1.0f / l_i[f][r];
                const int q = qblk * 128 + wave * 32 + f * 16 + lq * 4 + r;
                const size_t token = (size_t)bidx * 2048 + q;
#pragma unroll
                for (int ni = 0; ni < 4; ni++)
                    aout[token * 1024 + h * 64 + ni * 16 + lr] = f2bf(acc[f][ni][r] * rinv);
            }
    }
}

// ---------------- launch ----------------
extern "C" void kernel_launch(void* const* d_in, const int* in_sizes, int n_in,
                              void* d_out, int out_size, void* d_ws, size_t ws_size,
                              hipStream_t stream) {
    const float* x      = (const float*)d_in[0];
    const float* qkv_w  = (const float*)d_in[1];
    const float* qkv_b  = (const float*)d_in[2];
    const float* out_w  = (const float*)d_in[3];
    const float* out_b  = (const float*)d_in[4];
    const float* ffn1_w = (const float*)d_in[5];
    const float* ffn1_b = (const float*)d_in[6];
    const float* ffn2_w = (const float*)d_in[7];
    const float* ffn2_b = (const float*)d_in[8];
    const float* ln1_g  = (const float*)d_in[9];
    const float* ln1_b  = (const float*)d_in[10];
    const float* ln2_g  = (const float*)d_in[11];
    const float* ln2_b  = (const float*)d_in[12];
    float* out = (float*)d_out;
    char* W = (char*)d_ws;

    unsigned short* normed = (unsigned short*)(W);
    unsigned short* x1     = (unsigned short*)(W + 16777216);
    unsigned short* qbuf   = (unsigned short*)(W + 33554432);
    unsigned short* kbuf   = (unsigned short*)(W + 50331648);
    unsigned short* vbuf   = (unsigned short*)(W + 67108864);
    unsigned short* attnb  = (unsigned short*)(W + 83886080);
    unsigned short* hff    = (unsigned short*)(W + 33554432);  // reuses q/k/v/attn (dead)
    unsigned short* qkv_wt = (unsigned short*)(W + 100663296);
    unsigned short* out_wt = (unsigned short*)(W + 106954752);
    unsigned short* f1_wt  = (unsigned short*)(W + 109051904);
    unsigned short* f2_wt  = (unsigned short*)(W + 117440512);

    transpose_cast_kernel<<<dim3(3072 / 32, 1024 / 32), 256, 0, stream>>>(qkv_w, qkv_wt, 1024, 3072);
    transpose_cast_kernel<<<dim3(1024 / 32, 1024 / 32), 256, 0, stream>>>(out_w, out_wt, 1024, 1024);
    transpose_cast_kernel<<<dim3(4096 / 32, 1024 / 32), 256, 0, stream>>>(ffn1_w, f1_wt, 1024, 4096);
    transpose_cast_kernel<<<dim3(1024 / 32, 4096 / 32), 256, 0, stream>>>(ffn2_w, f2_wt, 4096, 1024);

    ln_f32_kernel<<<dim3(8192), 256, 0, stream>>>(x, ln1_g, ln1_b, normed);
    gemm_bt<EPI_QKV, float, unsigned short><<<dim3(3072 / 128, 8192 / 128), 256, 0, stream>>>(
        normed, qkv_wt, qkv_b, nullptr, qbuf, kbuf, vbuf, 8192, 3072, 1024);
    attn_kernel<<<dim3(8, 64), 256, 0, stream>>>(qbuf, kbuf, vbuf, attnb);
    gemm_bt<EPI_RES, float, unsigned short><<<dim3(1024 / 128, 8192 / 128), 256, 0, stream>>>(
        attnb, out_wt, out_b, x, x1, nullptr, nullptr, 8192, 1024, 1024);
    ln_bf16_kernel<<<dim3(8192), 256, 0, stream>>>(x1, ln2_g, ln2_b, normed);
    gemm_bt<EPI_GELU, float, unsigned short><<<dim3(4096 / 128, 8192 / 128), 256, 0, stream>>>(
        normed, f1_wt, ffn1_b, nullptr, hff, nullptr, nullptr, 8192, 4096, 1024);
    gemm_bt<EPI_RES, unsigned short, float><<<dim3(1024 / 128, 8192 / 128), 256, 0, stream>>>(
        hff, f2_wt, ffn2_b, x1, out, nullptr, nullptr, 8192, 1024, 4096);
}

// Round 9
// 602.118 us; speedup vs baseline: 1.3015x; 1.0463x over previous
//
#include <hip/hip_runtime.h>
#include <hip/hip_bf16.h>
#include <math.h>

typedef __attribute__((ext_vector_type(8))) short short8;
typedef __attribute__((ext_vector_type(4))) float f32x4;

__device__ __forceinline__ float bf2f(unsigned short u) {
    union { unsigned int i; float f; } c; c.i = ((unsigned int)u) << 16; return c.f;
}
__device__ __forceinline__ unsigned short f2bf(float f) {
    union { float f; unsigned int i; } c; c.f = f;
    unsigned int i = c.i;
    unsigned int r = (i + 0x7FFFu + ((i >> 16) & 1u)) >> 16;
    return (unsigned short)r;
}
__device__ __forceinline__ float fexp2(float x) { return __builtin_amdgcn_exp2f(x); }

// vectorized 8-wide helpers for epilogue readback
__device__ __forceinline__ void load8(const unsigned short* p, float* v) {
    short8 s = *(const short8*)p;
#pragma unroll
    for (int i = 0; i < 8; i++) v[i] = bf2f((unsigned short)s[i]);
}
__device__ __forceinline__ void load8(const float* p, float* v) {
    f32x4 a = ((const f32x4*)p)[0], b = ((const f32x4*)p)[1];
    v[0] = a[0]; v[1] = a[1]; v[2] = a[2]; v[3] = a[3];
    v[4] = b[0]; v[5] = b[1]; v[6] = b[2]; v[7] = b[3];
}
__device__ __forceinline__ void store8(unsigned short* p, const float* v) {
    short8 s;
#pragma unroll
    for (int i = 0; i < 8; i++) s[i] = (short)f2bf(v[i]);
    *(short8*)p = s;
}
__device__ __forceinline__ void store8(float* p, const float* v) {
    f32x4 a, b;
    a[0] = v[0]; a[1] = v[1]; a[2] = v[2]; a[3] = v[3];
    b[0] = v[4]; b[1] = v[5]; b[2] = v[6]; b[3] = v[7];
    ((f32x4*)p)[0] = a; ((f32x4*)p)[1] = b;
}

// ---------------- LayerNorm (fp32 input) -> bf16 output ----------------
__global__ __launch_bounds__(256) void ln_f32_kernel(
    const float* __restrict__ x, const float* __restrict__ g,
    const float* __restrict__ b, unsigned short* __restrict__ out) {
    const int row = blockIdx.x;
    const int t = threadIdx.x;
    const float* xr = x + (size_t)row * 1024;
    float4 raw = ((const float4*)xr)[t];
    float v0 = raw.x, v1 = raw.y, v2 = raw.z, v3 = raw.w;
    float s = v0 + v1 + v2 + v3;
    float ss = v0 * v0 + v1 * v1 + v2 * v2 + v3 * v3;
    for (int off = 32; off > 0; off >>= 1) {
        s += __shfl_down(s, off);
        ss += __shfl_down(ss, off);
    }
    __shared__ float red[8];
    __shared__ float stat[2];
    const int wave = t >> 6, lane = t & 63;
    if (lane == 0) { red[wave] = s; red[4 + wave] = ss; }
    __syncthreads();
    if (t == 0) {
        float st = red[0] + red[1] + red[2] + red[3];
        float sst = red[4] + red[5] + red[6] + red[7];
        float mu = st * (1.0f / 1024.0f);
        float var = sst * (1.0f / 1024.0f) - mu * mu;
        stat[0] = mu; stat[1] = rsqrtf(var + 1e-5f);
    }
    __syncthreads();
    const float mu = stat[0], rstd = stat[1];
    float4 gr = ((const float4*)g)[t];
    float4 br = ((const float4*)b)[t];
    ushort4 o;
    o.x = f2bf((v0 - mu) * rstd * gr.x + br.x);
    o.y = f2bf((v1 - mu) * rstd * gr.y + br.y);
    o.z = f2bf((v2 - mu) * rstd * gr.z + br.z);
    o.w = f2bf((v3 - mu) * rstd * gr.w + br.w);
    ((ushort4*)(out + (size_t)row * 1024))[t] = o;
}

// ---------------- LayerNorm (bf16 input) -> bf16 output ----------------
__global__ __launch_bounds__(256) void ln_bf16_kernel(
    const unsigned short* __restrict__ x, const float* __restrict__ g,
    const float* __restrict__ b, unsigned short* __restrict__ out) {
    const int row = blockIdx.x;
    const int t = threadIdx.x;
    const unsigned short* xr = x + (size_t)row * 1024;
    ushort4 raw = ((const ushort4*)xr)[t];
    float v0 = bf2f(raw.x), v1 = bf2f(raw.y), v2 = bf2f(raw.z), v3 = bf2f(raw.w);
    float s = v0 + v1 + v2 + v3;
    float ss = v0 * v0 + v1 * v1 + v2 * v2 + v3 * v3;
    for (int off = 32; off > 0; off >>= 1) {
        s += __shfl_down(s, off);
        ss += __shfl_down(ss, off);
    }
    __shared__ float red[8];
    __shared__ float stat[2];
    const int wave = t >> 6, lane = t & 63;
    if (lane == 0) { red[wave] = s; red[4 + wave] = ss; }
    __syncthreads();
    if (t == 0) {
        float st = red[0] + red[1] + red[2] + red[3];
        float sst = red[4] + red[5] + red[6] + red[7];
        float mu = st * (1.0f / 1024.0f);
        float var = sst * (1.0f / 1024.0f) - mu * mu;
        stat[0] = mu; stat[1] = rsqrtf(var + 1e-5f);
    }
    __syncthreads();
    const float mu = stat[0], rstd = stat[1];
    float4 gr = ((const float4*)g)[t];
    float4 br = ((const float4*)b)[t];
    ushort4 o;
    o.x = f2bf((v0 - mu) * rstd * gr.x + br.x);
    o.y = f2bf((v1 - mu) * rstd * gr.y + br.y);
    o.z = f2bf((v2 - mu) * rstd * gr.z + br.z);
    o.w = f2bf((v3 - mu) * rstd * gr.w + br.w);
    ((ushort4*)(out + (size_t)row * 1024))[t] = o;
}

// ---------------- Transpose+cast: fp32 in[R][C] -> bf16 out[C][R] ----------------
__global__ __launch_bounds__(256) void transpose_cast_kernel(
    const float* __restrict__ in, unsigned short* __restrict__ out, int R, int C) {
    __shared__ unsigned short tile[32][33];
    const int bx = blockIdx.x * 32, by = blockIdx.y * 32;
    const int tx = threadIdx.x & 31, ty = threadIdx.x >> 5;
    for (int i = 0; i < 32; i += 8)
        tile[ty + i][tx] = f2bf(in[(size_t)(by + ty + i) * C + bx + tx]);
    __syncthreads();
    for (int i = 0; i < 32; i += 8)
        out[(size_t)(bx + ty + i) * R + by + tx] = tile[tx][ty + i];
}

// ---------------- GEMM: C[M,N] = A[M,K] * Bt[N,K]^T + bias, fused epilogues ----
// 128x128 tile, BK=32, 4 waves (2x2), 16x16x32 bf16 MFMA.
// Double-buffered LDS, ONE barrier per K-iter; k+1 global loads issued before
// the barrier so their latency spans a full iteration.
// Epilogue stages C through LDS (reusing staging space) -> coalesced writes,
// with transposed staging for the V^T output of the QKV epilogue.
enum { EPI_QKV = 0, EPI_RES = 1, EPI_GELU = 2 };

template <int EPI, typename RT, typename OT>
__global__ __launch_bounds__(256) void gemm_bt(
    const unsigned short* __restrict__ A, const unsigned short* __restrict__ Bt,
    const float* __restrict__ bias, const RT* __restrict__ res,
    OT* __restrict__ o0, unsigned short* __restrict__ o1,
    unsigned short* __restrict__ o2, int M, int N, int K) {
    constexpr int LDW = 40;   // staging row pitch (shorts)
    constexpr int LE = 136;   // epilogue row pitch (shorts)
    __shared__ __align__(16) unsigned short SMEM[20480];  // 40 KB
    const int t = threadIdx.x;
    const int wave = t >> 6, lane = t & 63;
    const int lr = lane & 15, lq = lane >> 4;
    const int wm = (wave >> 1) * 64, wn = (wave & 1) * 64;
    const int m0 = blockIdx.y * 128, n0 = blockIdx.x * 128;
    f32x4 acc[4][4] = {};
    const int arow = t >> 2, acol = (t & 3) << 3;
    const unsigned short* ag = A + (size_t)(m0 + arow) * K + acol;
    const unsigned short* bg = Bt + (size_t)(n0 + arow) * K + acol;
    const size_t rstride = (size_t)64 * K;
    short8 a0 = *(const short8*)(ag);
    short8 a1 = *(const short8*)(ag + rstride);
    short8 b0 = *(const short8*)(bg);
    short8 b1 = *(const short8*)(bg + rstride);
    const int nit = K >> 5;
    for (int it = 0; it < nit; ++it) {
        const int buf = (it & 1) * 10240;  // double-buffer offset (no pointer table)
        unsigned short* As = SMEM + buf;
        unsigned short* Bs = SMEM + buf + 5120;
        *(short8*)(As + arow * LDW + acol) = a0;
        *(short8*)(As + (arow + 64) * LDW + acol) = a1;
        *(short8*)(Bs + arow * LDW + acol) = b0;
        *(short8*)(Bs + (arow + 64) * LDW + acol) = b1;
        if (it + 1 < nit) {  // full-iteration latency window
            const int k0 = (it + 1) << 5;
            a0 = *(const short8*)(ag + k0);
            a1 = *(const short8*)(ag + rstride + k0);
            b0 = *(const short8*)(bg + k0);
            b1 = *(const short8*)(bg + rstride + k0);
        }
        __syncthreads();
        short8 af[4], bfr[4];
#pragma unroll
        for (int i = 0; i < 4; i++) af[i] = *(const short8*)(As + (wm + i * 16 + lr) * LDW + lq * 8);
#pragma unroll
        for (int i = 0; i < 4; i++) bfr[i] = *(const short8*)(Bs + (wn + i * 16 + lr) * LDW + lq * 8);
#pragma unroll
        for (int mi = 0; mi < 4; mi++)
#pragma unroll
            for (int ni = 0; ni < 4; ni++)
                acc[mi][ni] = __builtin_amdgcn_mfma_f32_16x16x32_bf16(af[mi], bfr[ni], acc[mi][ni], 0, 0, 0);
    }
    // ---- epilogue: bias (+gelu) -> LDS stage -> coalesced writeback ----
    __syncthreads();  // staging buffers now free for reuse
    const bool vreg = (EPI == EPI_QKV) && (n0 >= 2048);
#pragma unroll
    for (int ni = 0; ni < 4; ni++) {
        const int col = wn + ni * 16 + lr;
        const float bv = bias[n0 + col];
#pragma unroll
        for (int mi = 0; mi < 4; mi++) {
#pragma unroll
            for (int r = 0; r < 4; r++) {
                const int row = wm + mi * 16 + lq * 4 + r;
                float val = acc[mi][ni][r] + bv;
                if (EPI == EPI_GELU)
                    val = 0.5f * val * (1.0f + erff(val * 0.70710678118654752f));
                if (vreg) SMEM[col * LE + row] = f2bf(val);
                else      SMEM[row * LE + col] = f2bf(val);
            }
        }
    }
    __syncthreads();
    const int rr = t >> 1, half = (t & 1) * 64;
    if (EPI == EPI_RES || EPI == EPI_GELU) {
        const size_t base = (size_t)(m0 + rr) * N + n0 + half;
        const unsigned short* src = SMEM + rr * LE + half;
#pragma unroll
        for (int j = 0; j < 8; j++) {
            float v[8];
            load8(src + j * 8, v);
            if (EPI == EPI_RES) {
                float rv[8];
                load8(res + base + j * 8, rv);
#pragma unroll
                for (int i = 0; i < 8; i++) v[i] += rv[i];
            }
            store8(o0 + base + j * 8, v);
        }
    } else if (!vreg) {  // q/k: out[(bh*2048+s)*64 + d]
        const int gcol0 = n0 + half;
        const int which = gcol0 >> 10;          // 0=q, 1=k (uniform per block half)
        const int hn = (gcol0 & 1023) >> 6;
        const int grow = m0 + rr;
        const size_t bh = (size_t)((grow >> 11) * 16 + hn);
        unsigned short* dst = (which == 0) ? (unsigned short*)o0 : o1;
        dst += (bh * 2048 + (grow & 2047)) * 64;
        const unsigned short* src = SMEM + rr * LE + half;
#pragma unroll
        for (int j = 0; j < 8; j++)
            *(short8*)(dst + j * 8) = *(const short8*)(src + j * 8);
    } else {  // v^T: out[(bh*64+d)*2048 + s], staged transposed
        const int c = rr;
        const int rem = (n0 + c) - 2048;
        const int hn = rem >> 6, d = rem & 63;
        const size_t bh = (size_t)((m0 >> 11) * 16 + hn);
        unsigned short* dst = o2 + (bh * 64 + d) * 2048 + (m0 & 2047) + half;
        const unsigned short* src = SMEM + c * LE + half;
#pragma unroll
        for (int j = 0; j < 8; j++)
            *(short8*)(dst + j * 8) = *(const short8*)(src + j * 8);
    }
}

// ---------------- Flash attention v3, causal. Hd=64, S=2048, BH=64 ----------------
__global__ __launch_bounds__(256) void attn_kernel(
    const unsigned short* __restrict__ qb, const unsigned short* __restrict__ kb,
    const unsigned short* __restrict__ vtb, unsigned short* __restrict__ aout) {
    const int bx = blockIdx.x;  // 0..7
    const int bh = blockIdx.y;
    const int bidx = bh >> 4, h = bh & 15;
    const int t = threadIdx.x, wave = t >> 6, lane = t & 63;
    const int lr = lane & 15, lq = lane >> 4;
    __shared__ __align__(16) unsigned short Ks[64 * 68];
    __shared__ __align__(16) unsigned short Vs[64 * 68];
    __shared__ __align__(16) unsigned short Ps[4][32 * 68];
    const unsigned short* kbase = kb + (size_t)bh * 2048 * 64;
    const unsigned short* vbase = vtb + (size_t)bh * 64 * 2048;
    const int srow = t >> 3, scol = (t & 7) * 8;
    const float kQScale = 0.125f * 1.44269504088896f;

    for (int phase = 0; phase < 2; phase++) {
        const int qblk = phase ? (15 - bx) : bx;
        const unsigned short* qbase = qb + ((size_t)bh * 2048 + qblk * 128 + wave * 32) * 64;
        short8 qf[2][2];
#pragma unroll
        for (int f = 0; f < 2; f++)
#pragma unroll
            for (int c = 0; c < 2; c++) {
                short8 raw = *(const short8*)(qbase + (f * 16 + lr) * 64 + c * 32 + lq * 8);
                short8 sc;
#pragma unroll
                for (int j = 0; j < 8; j++)
                    sc[j] = (short)f2bf(bf2f((unsigned short)raw[j]) * kQScale);
                qf[f][c] = sc;
            }
        f32x4 acc[2][4] = {};
        float m_i[2][4], l_i[2][4];
#pragma unroll
        for (int f = 0; f < 2; f++)
#pragma unroll
            for (int r = 0; r < 4; r++) { m_i[f][r] = -1e30f; l_i[f][r] = 0.0f; }
        const int wave_q0 = qblk * 128 + wave * 32;
        const int nkt = 2 * (qblk + 1);
        short8 kr0 = *(const short8*)(kbase + t * 8);
        short8 kr1 = *(const short8*)(kbase + 2048 + t * 8);
        short8 vr0 = *(const short8*)(vbase + (size_t)srow * 2048 + scol);
        short8 vr1 = *(const short8*)(vbase + (size_t)(32 + srow) * 2048 + scol);
        for (int kt = 0; kt < nkt; kt++) {
            __syncthreads();
            *(short8*)(Ks + srow * 68 + scol) = kr0;
            *(short8*)(Ks + (32 + srow) * 68 + scol) = kr1;
            *(short8*)(Vs + srow * 68 + scol) = vr0;
            *(short8*)(Vs + (32 + srow) * 68 + scol) = vr1;
            __syncthreads();
            if (kt + 1 < nkt) {
                const unsigned short* kg = kbase + (kt + 1) * 4096;
                kr0 = *(const short8*)(kg + t * 8);
                kr1 = *(const short8*)(kg + 2048 + t * 8);
                vr0 = *(const short8*)(vbase + (size_t)srow * 2048 + (kt + 1) * 64 + scol);
                vr1 = *(const short8*)(vbase + (size_t)(32 + srow) * 2048 + (kt + 1) * 64 + scol);
            }
            if (kt * 64 <= wave_q0 + 31) {
                f32x4 sa[2][4];
#pragma unroll
                for (int ni = 0; ni < 4; ni++) {
                    short8 kf0 = *(const short8*)(Ks + (ni * 16 + lr) * 68 + lq * 8);
                    short8 kf1 = *(const short8*)(Ks + (ni * 16 + lr) * 68 + 32 + lq * 8);
#pragma unroll
                    for (int f = 0; f < 2; f++) {
                        f32x4 z = {};
                        z = __builtin_amdgcn_mfma_f32_16x16x32_bf16(qf[f][0], kf0, z, 0, 0, 0);
                        sa[f][ni] = __builtin_amdgcn_mfma_f32_16x16x32_bf16(qf[f][1], kf1, z, 0, 0, 0);
                    }
                }
                const bool needmask = (kt * 64 + 63 > wave_q0);
                if (needmask) {
#pragma unroll
                    for (int f = 0; f < 2; f++) {
                        const int qrow0 = wave_q0 + f * 16 + lq * 4;
#pragma unroll
                        for (int ni = 0; ni < 4; ni++) {
                            const int kcol = kt * 64 + ni * 16 + lr;
#pragma unroll
                            for (int r = 0; r < 4; r++)
                                if (kcol > qrow0 + r) sa[f][ni][r] = -1e30f;
                        }
                    }
                }
#pragma unroll
                for (int f = 0; f < 2; f++) {
                    float mcur[4], alpha[4], rsum[4];
#pragma unroll
                    for (int r = 0; r < 4; r++)
                        mcur[r] = fmaxf(fmaxf(sa[f][0][r], sa[f][1][r]), fmaxf(sa[f][2][r], sa[f][3][r]));
#pragma unroll
                    for (int r = 0; r < 4; r++) {
#pragma unroll
                        for (int off = 1; off < 16; off <<= 1) mcur[r] = fmaxf(mcur[r], __shfl_xor(mcur[r], off));
                        const float mn = fmaxf(m_i[f][r], mcur[r]);
                        alpha[r] = fexp2(m_i[f][r] - mn);
                        m_i[f][r] = mn;
                        rsum[r] = 0.0f;
                    }
#pragma unroll
                    for (int ni = 0; ni < 4; ni++)
#pragma unroll
                        for (int r = 0; r < 4; r++) {
                            const float p = fexp2(sa[f][ni][r] - m_i[f][r]);
                            Ps[wave][(f * 16 + lq * 4 + r) * 68 + ni * 16 + lr] = f2bf(p);
                            rsum[r] += p;
                        }
#pragma unroll
                    for (int r = 0; r < 4; r++) {
#pragma unroll
                        for (int off = 1; off < 16; off <<= 1) rsum[r] += __shfl_xor(rsum[r], off);
                        l_i[f][r] = l_i[f][r] * alpha[r] + rsum[r];
#pragma unroll
                        for (int ni = 0; ni < 4; ni++) acc[f][ni][r] *= alpha[r];
                    }
                }
                short8 pf[2][2];
#pragma unroll
                for (int f = 0; f < 2; f++)
#pragma unroll
                    for (int c = 0; c < 2; c++)
                        pf[f][c] = *(const short8*)(&Ps[wave][(f * 16 + lr) * 68 + c * 32 + lq * 8]);
#pragma unroll
                for (int ni = 0; ni < 4; ni++) {
                    short8 vf0 = *(const short8*)(Vs + (ni * 16 + lr) * 68 + lq * 8);
                    short8 vf1 = *(const short8*)(Vs + (ni * 16 + lr) * 68 + 32 + lq * 8);
#pragma unroll
                    for (int f = 0; f < 2; f++) {
                        acc[f][ni] = __builtin_amdgcn_mfma_f32_16x16x32_bf16(pf[f][0], vf0, acc[f][ni], 0, 0, 0);
                        acc[f][ni] = __builtin_amdgcn_mfma_f32_16x16x32_bf16(pf[f][1], vf1, acc[f][ni], 0, 0, 0);
                    }
                }
            }
        }
#pragma unroll
        for (int f = 0; f < 2; f++)
#pragma unroll
            for (int r = 0; r < 4; r++) {
                const float rinv = 1.0f / l_i[f][r];
                const int q = qblk * 128 + wave * 32 + f * 16 + lq * 4 + r;
                const size_t token = (size_t)bidx * 2048 + q;
#pragma unroll
                for (int ni = 0; ni < 4; ni++)
                    aout[token * 1024 + h * 64 + ni * 16 + lr] = f2bf(acc[f][ni][r] * rinv);
            }
    }
}

// ---------------- launch ----------------
extern "C" void kernel_launch(void* const* d_in, const int* in_sizes, int n_in,
                              void* d_out, int out_size, void* d_ws, size_t ws_size,
                              hipStream_t stream) {
    const float* x      = (const float*)d_in[0];
    const float* qkv_w  = (const float*)d_in[1];
    const float* qkv_b  = (const float*)d_in[2];
    const float* out_w  = (const float*)d_in[3];
    const float* out_b  = (const float*)d_in[4];
    const float* ffn1_w = (const float*)d_in[5];
    const float* ffn1_b = (const float*)d_in[6];
    const float* ffn2_w = (const float*)d_in[7];
    const float* ffn2_b = (const float*)d_in[8];
    const float* ln1_g  = (const float*)d_in[9];
    const float* ln1_b  = (const float*)d_in[10];
    const float* ln2_g  = (const float*)d_in[11];
    const float* ln2_b  = (const float*)d_in[12];
    float* out = (float*)d_out;
    char* W = (char*)d_ws;

    unsigned short* normed = (unsigned short*)(W);
    unsigned short* x1     = (unsigned short*)(W + 16777216);
    unsigned short* qbuf   = (unsigned short*)(W + 33554432);
    unsigned short* kbuf   = (unsigned short*)(W + 50331648);
    unsigned short* vbuf   = (unsigned short*)(W + 67108864);
    unsigned short* attnb  = (unsigned short*)(W + 83886080);
    unsigned short* hff    = (unsigned short*)(W + 33554432);  // reuses q/k/v/attn (dead)
    unsigned short* qkv_wt = (unsigned short*)(W + 100663296);
    unsigned short* out_wt = (unsigned short*)(W + 106954752);
    unsigned short* f1_wt  = (unsigned short*)(W + 109051904);
    unsigned short* f2_wt  = (unsigned short*)(W + 117440512);

    transpose_cast_kernel<<<dim3(3072 / 32, 1024 / 32), 256, 0, stream>>>(qkv_w, qkv_wt, 1024, 3072);
    transpose_cast_kernel<<<dim3(1024 / 32, 1024 / 32), 256, 0, stream>>>(out_w, out_wt, 1024, 1024);
    transpose_cast_kernel<<<dim3(4096 / 32, 1024 / 32), 256, 0, stream>>>(ffn1_w, f1_wt, 1024, 4096);
    transpose_cast_kernel<<<dim3(1024 / 32, 4096 / 32), 256, 0, stream>>>(ffn2_w, f2_wt, 4096, 1024);

    ln_f32_kernel<<<dim3(8192), 256, 0, stream>>>(x, ln1_g, ln1_b, normed);
    gemm_bt<EPI_QKV, float, unsigned short><<<dim3(3072 / 128, 8192 / 128), 256, 0, stream>>>(
        normed, qkv_wt, qkv_b, nullptr, qbuf, kbuf, vbuf, 8192, 3072, 1024);
    attn_kernel<<<dim3(8, 64), 256, 0, stream>>>(qbuf, kbuf, vbuf, attnb);
    gemm_bt<EPI_RES, float, unsigned short><<<dim3(1024 / 128, 8192 / 128), 256, 0, stream>>>(
        attnb, out_wt, out_b, x, x1, nullptr, nullptr, 8192, 1024, 1024);
    ln_bf16_kernel<<<dim3(8192), 256, 0, stream>>>(x1, ln2_g, ln2_b, normed);
    gemm_bt<EPI_GELU, float, unsigned short><<<dim3(4096 / 128, 8192 / 128), 256, 0, stream>>>(
        normed, f1_wt, ffn1_b, nullptr, hff, nullptr, nullptr, 8192, 4096, 1024);
    gemm_bt<EPI_RES, unsigned short, float><<<dim3(1024 / 128, 8192 / 128), 256, 0, stream>>>(
        hff, f2_wt, ffn2_b, x1, out, nullptr, nullptr, 8192, 1024, 4096);
}